// Round 11
// baseline (272.046 us; speedup 1.0000x reference)
//
#include <hip/hip_runtime.h>
#include <math.h>
#include <stdint.h>

// Shapes (fixed by the reference)
// N=10000, E=100000, G=64, NB=16, EMB=16, S=8, COUT=16, LMAX=2
// WNUM = 3*16*8*8 = 3072 ; ef width = 16 + 48 + 144 = 208
// Per-edge compact result: m[48] (l*16+o) + n[3], stored as 52 floats.
//
// Main contraction as a fused GEMM via MFMA:
//   m[e][lo] = sum_ab o[e][ab] * ( sum_c h[e][c] * w3[c][lo*64+ab] ) + bias
// B-fragments are now BLOCK-SHARED: each 12KB K-chunk is loaded ONCE per block
// via global_load_lds (3 insts/wave, 4 waves) into a 3-slot LDS ring; waves
// read via ds_read_b128. Counted s_waitcnt vmcnt(3) + raw s_barrier keep 2
// chunks in flight (never drain-0). o is recomputed per step from compact
// fs/fd (10.2KB LDS). Bias = ring chunk 64 (no register B buffer).

typedef float  f32x4  __attribute__((ext_vector_type(4)));
typedef short  s16x8  __attribute__((ext_vector_type(8)));
typedef __bf16 bf16x8 __attribute__((ext_vector_type(8)));

__device__ __forceinline__ float silu_f(float x) {
    return x / (1.0f + __expf(-x));
}

// split 8 f32 (two f32x4, k-local order j=0..7) into bf16 hi + lo fragments
__device__ __forceinline__ void split8(f32x4 a, f32x4 b, s16x8& hi, s16x8& lo) {
    bf16x8 h8, l8;
    #pragma unroll
    for (int i = 0; i < 4; ++i) {
        float z = a[i]; __bf16 zh = (__bf16)z; h8[i] = zh; l8[i] = (__bf16)(z - (float)zh);
        float y = b[i]; __bf16 yh = (__bf16)y; h8[4 + i] = yh; l8[4 + i] = (__bf16)(y - (float)yh);
    }
    hi = __builtin_bit_cast(s16x8, h8);
    lo = __builtin_bit_cast(s16x8, l8);
}

// ---------------- kernel 1 (fused setup): prep wz | node Ai | edge_dst hist ----------------
// K-step s (0..129): 32 k-values. s<128: ab=s>>1, c=(s&1)*32+kl. s>=128: ab=(s-128)*32+kl.
// Fragment lane l: col lo = t*16 + (l&15); kl = (l>>4)*8 + j.
// wz[ ((s*3 + t)*2 + plane)*512 + l*8 + j ]  (ushort bf16)
__global__ __launch_bounds__(256) void k_setup(const float* __restrict__ w3,
                                               const float* __restrict__ b3,
                                               ushort* __restrict__ wz,
                                               const int* __restrict__ A,
                                               const float* __restrict__ embt,
                                               const float* __restrict__ w1,
                                               const float* __restrict__ b1,
                                               const float* __restrict__ w2,
                                               const float* __restrict__ b2,
                                               float* __restrict__ Ai,
                                               const int* __restrict__ edst,
                                               int* __restrict__ deg,
                                               int N, int E, int aiB) {
    const int b = blockIdx.x;
    const int tid = threadIdx.x;
    if (b < 780) {                         // ---- prep: 780*256 = 199680 = 130*3*512
        int t = b * 256 + tid;
        int j    = t & 7;
        int l    = (t >> 3) & 63;
        int rest = t >> 9;          // s*3 + tt
        int tt   = rest % 3;
        int s    = rest / 3;
        int lo   = tt * 16 + (l & 15);
        int kl   = (l >> 4) * 8 + j;
        float v;
        if (s < 128) {
            int ab = s >> 1;
            int c  = (s & 1) * 32 + kl;
            v = w3[c * 3072 + lo * 64 + ab];
        } else {
            int ab = (s - 128) * 32 + kl;
            v = b3[lo * 64 + ab];
        }
        __bf16 hi  = (__bf16)v;
        __bf16 lor = (__bf16)(v - (float)hi);
        size_t base = (size_t)(s * 3 + tt) * 2 * 512 + l * 8 + j;
        wz[base]       = __builtin_bit_cast(ushort, hi);
        wz[base + 512] = __builtin_bit_cast(ushort, lor);
    } else if (b < 780 + aiB) {            // ---- node Ai
        int i = (b - 780) * 256 + tid;
        if (i >= N) return;
        float e[16];
        const float* er = embt + A[i] * 16;
        #pragma unroll
        for (int k = 0; k < 16; ++k) e[k] = er[k];
        float h1[64];
        #pragma unroll
        for (int j = 0; j < 64; ++j) {
            float a = b1[j];
            #pragma unroll
            for (int k = 0; k < 16; ++k) a = fmaf(e[k], w1[k * 64 + j], a);
            h1[j] = silu_f(a);
        }
        #pragma unroll
        for (int o = 0; o < 8; ++o) {
            float a = b2[o];
            #pragma unroll
            for (int j = 0; j < 64; ++j) a = fmaf(h1[j], w2[j * 8 + o], a);
            Ai[i * 8 + o] = a;
        }
    } else {                               // ---- histogram of edge_dst
        int e = (b - 780 - aiB) * 256 + tid;
        if (e < E) atomicAdd(&deg[edst[e]], 1);
    }
}

// ---------------- kernel 2: single-block exclusive scan (N=10000), 1024 threads ----------------
__global__ __launch_bounds__(1024) void k_scan(const int* __restrict__ deg,
                                               int* __restrict__ offs,
                                               int* __restrict__ cursor, int N) {
    __shared__ int part[1024];
    const int t = threadIdx.x;
    const int chunk = (N + 1023) / 1024;
    const int beg = t * chunk;
    const int end = min(beg + chunk, N);
    int s = 0;
    for (int i = beg; i < end; ++i) s += deg[i];
    part[t] = s;
    __syncthreads();
    for (int off = 1; off < 1024; off <<= 1) {
        int v = (t >= off) ? part[t - off] : 0;
        __syncthreads();
        part[t] += v;
        __syncthreads();
    }
    int run = (t == 0) ? 0 : part[t - 1];
    for (int i = beg; i < end; ++i) {
        offs[i] = run;
        cursor[i] = run;
        run += deg[i];
    }
    if (t == 1023) offs[N] = part[1023];
}

// ---------------- kernel 3: per-edge compute via MFMA, LDS B-ring ----------------
// Block = 256 threads = 4 waves = 128 edges (M=32 per wave: 2 x 16-row tiles).
// After the front end, the h-staging LDS becomes a 3-slot B ring (12KB/slot).
// Per u: issue chunk u+2 (3 x global_load_lds/wave), compute chunk u from LDS,
// s_waitcnt vmcnt(3) (counted, never 0 mid-loop) + raw s_barrier.
// o recomputed per step from compact s_fsfd. Bias = ring chunk 64.
__global__ __launch_bounds__(256, 3) void k_edge(
    const float* __restrict__ pos, const int* __restrict__ batch,
    const int* __restrict__ esrc, const int* __restrict__ edst,
    const float* __restrict__ eshift, const float* __restrict__ cell,
    const float* __restrict__ fw1, const float* __restrict__ fb1,
    const float* __restrict__ fw2, const float* __restrict__ fb2,
    const ushort* __restrict__ wz,
    const float* __restrict__ Ai, float* __restrict__ ef,
    int* __restrict__ cursor, int* __restrict__ eidx, int E) {

    __shared__ __align__(16) float s_uni[9216];        // 36864B: h1@65 -> h@68 -> B ring 3x12288B
    __shared__ __align__(16) float s_fsfd[128 * 20];   // 10240B: fs[8]|fd[8] per edge (pad to 20)

    const int tid  = threadIdx.x;
    const int lane = tid & 63;
    const int w    = __builtin_amdgcn_readfirstlane(tid >> 6);   // wave id
    const int e0   = blockIdx.x * 128;
    const int j0   = w * 16;                                     // c-chunk
    const int g    = lane >> 4;                                  // k-group

    // ---- front end, two rounds of 64 edges (r7 structure) ----
    #pragma unroll
    for (int rr = 0; rr < 2; ++rr) {
        const int e = e0 + rr * 64 + lane;
        const bool valid = (e < E);
        const int ec = valid ? e : (E - 1);
        const int src = esrc[ec];
        const int dst = edst[ec];

        const int g0 = batch[src];
        const float s0 = eshift[ec * 3 + 0], s1 = eshift[ec * 3 + 1], s2 = eshift[ec * 3 + 2];
        const float* cl = cell + g0 * 9;
        float vx = pos[dst * 3 + 0] - pos[src * 3 + 0] + s0 * cl[0] + s1 * cl[3] + s2 * cl[6];
        float vy = pos[dst * 3 + 1] - pos[src * 3 + 1] + s0 * cl[1] + s1 * cl[4] + s2 * cl[7];
        float vz = pos[dst * 3 + 2] - pos[src * 3 + 2] + s0 * cl[2] + s1 * cl[5] + s2 * cl[8];
        float r = sqrtf(vx * vx + vy * vy + vz * vz);
        float rinv = 1.0f / fmaxf(r, 1e-9f);
        float nx = vx * rinv, ny = vy * rinv, nz = vz * rinv;

        float embv[16];
        const float step = 4.0f / 17.0f;
        const float sc = 4.0f / 1.12f;
        #pragma unroll
        for (int k = 0; k < 16; ++k) {
            float d = (r - (float)(k + 1) * step) / step;
            embv[k] = __expf(-d * d) * sc;
        }

        // h1 chunk -> s_uni (stride 65)
        const int hb = (rr * 64 + lane) * 65;
        #pragma unroll
        for (int jj = 0; jj < 16; ++jj) {
            const int j = j0 + jj;
            float a = fb1[j];
            #pragma unroll
            for (int k = 0; k < 16; ++k) a = fmaf(embv[k], fw1[k * 64 + j], a);
            s_uni[hb + j] = silu_f(a);
        }

        // fs/fd -> s_fsfd (wave 0 only); n + CSR scatter
        if (w == 0) {
            const float* As = Ai + (size_t)src * 8;
            const float* Ad = Ai + (size_t)dst * 8;
            float* fr = s_fsfd + (rr * 64 + lane) * 20;
            *reinterpret_cast<f32x4*>(fr)      = *reinterpret_cast<const f32x4*>(As);
            *reinterpret_cast<f32x4*>(fr + 4)  = *reinterpret_cast<const f32x4*>(As + 4);
            *reinterpret_cast<f32x4*>(fr + 8)  = *reinterpret_cast<const f32x4*>(Ad);
            *reinterpret_cast<f32x4*>(fr + 12) = *reinterpret_cast<const f32x4*>(Ad + 4);
            if (valid) {
                float* np = ef + (size_t)e * 52;
                np[48] = nx; np[49] = ny; np[50] = nz;
                int pp = atomicAdd(&cursor[dst], 1);
                eidx[pp] = e;
            }
        }
    }
    __syncthreads();

    // ---- hc chunks (registers) for both rounds ----
    float hcr[2][16];
    #pragma unroll
    for (int rr = 0; rr < 2; ++rr) {
        const int hb = (rr * 64 + lane) * 65;
        #pragma unroll
        for (int i = 0; i < 16; ++i) hcr[rr][i] = fb2[j0 + i];
        #pragma unroll 4
        for (int j = 0; j < 64; ++j) {
            const float v = s_uni[hb + j];
            const float* w2r = fw2 + j * 64 + j0;   // wave-uniform -> scalar
            #pragma unroll
            for (int i = 0; i < 16; ++i) hcr[rr][i] = fmaf(v, w2r[i], hcr[rr][i]);
        }
        #pragma unroll
        for (int i = 0; i < 16; ++i) hcr[rr][i] = silu_f(hcr[rr][i]);
    }
    __syncthreads();   // all h1 reads done -> rewrite region at stride 68

    #pragma unroll
    for (int rr = 0; rr < 2; ++rr) {
        const int hb = (rr * 64 + lane) * 68 + j0;
        #pragma unroll
        for (int i = 0; i < 16; ++i) s_uni[hb + i] = hcr[rr][i];
    }
    __syncthreads();

    // ---- extract per-lane A (h) fragments and O (bias) fragments ----
    const int mrow = w * 32 + (lane & 15);   // M-tile 0 row
    s16x8 AhF[2][2], AlF[2][2], OhF[2][2], OlF[2][2];
    #pragma unroll
    for (int mt = 0; mt < 2; ++mt) {
        const float* hr = s_uni + (mrow + mt * 16) * 68;
        f32x4 a0 = *reinterpret_cast<const f32x4*>(hr + g * 8);
        f32x4 a1 = *reinterpret_cast<const f32x4*>(hr + g * 8 + 4);
        split8(a0, a1, AhF[mt][0], AlF[mt][0]);
        f32x4 a2 = *reinterpret_cast<const f32x4*>(hr + 32 + g * 8);
        f32x4 a3 = *reinterpret_cast<const f32x4*>(hr + 32 + g * 8 + 4);
        split8(a2, a3, AhF[mt][1], AlF[mt][1]);
        // O: o[ab] = fs[ab>>3]*fd[ab&7]; sl0 -> fs[g], sl1 -> fs[4+g]
        const float* fr = s_fsfd + (mrow + mt * 16) * 20;
        float fsg  = fr[g];
        float fsg4 = fr[4 + g];
        f32x4 fda = *reinterpret_cast<const f32x4*>(fr + 8);
        f32x4 fdb = *reinterpret_cast<const f32x4*>(fr + 12);
        split8(fsg * fda,  fsg * fdb,  OhF[mt][0], OlF[mt][0]);
        split8(fsg4 * fda, fsg4 * fdb, OhF[mt][1], OlF[mt][1]);
    }

    // hand off s_uni to the B ring: all extraction ds_reads must be done
    asm volatile("s_waitcnt lgkmcnt(0)" ::: "memory");
    __builtin_amdgcn_s_barrier();
    __builtin_amdgcn_sched_barrier(0);

    ushort* ring = reinterpret_cast<ushort*>(s_uni);   // 3 slots x 6144 ushorts

    // wave w copies pieces [w*3, w*3+3) of chunk U (12KB) into slot S
#define ISSUE(U, S) { \
    const ushort* gsrc = wz + (size_t)(U) * 6144 + (w * 3) * 512 + lane * 8; \
    ushort* ldst = ring + (S) * 6144 + (w * 3) * 512; \
    __builtin_amdgcn_global_load_lds(gsrc,        ldst,        16, 0, 0); \
    __builtin_amdgcn_global_load_lds(gsrc + 512,  ldst + 512,  16, 0, 0); \
    __builtin_amdgcn_global_load_lds(gsrc + 1024, ldst + 1024, 16, 0, 0); }

    ISSUE(0, 0);
    ISSUE(1, 1);
    asm volatile("s_waitcnt vmcnt(3)" ::: "memory");   // slot0 landed; slot1 in flight
    __builtin_amdgcn_s_barrier();
    __builtin_amdgcn_sched_barrier(0);

    const int rb = w * 32 + (lane >> 4) * 4;   // first output row of this lane's D

    f32x4 acc[2][3];
    #pragma unroll
    for (int mt = 0; mt < 2; ++mt)
        #pragma unroll
        for (int t = 0; t < 3; ++t) acc[mt][t] = (f32x4){0.f, 0.f, 0.f, 0.f};

    float fs8[8];
    int cur = 0;
    for (int u = 0; u <= 64; ++u) {
        if (u < 63) {                       // keep ring 2 chunks ahead
            int s2 = cur + 2; if (s2 >= 3) s2 -= 3;
            ISSUE(u + 2, s2);
        }
        const ushort* BB = ring + cur * 6144;
        if (u < 64) {
            if ((u & 7) == 0) {             // fs changes every 8 steps
                const int q = u >> 3;
                #pragma unroll
                for (int i = 0; i < 4; ++i) {
                    fs8[i]     = s_fsfd[(rb + i) * 20 + q];
                    fs8[4 + i] = s_fsfd[(rb + 16 + i) * 20 + q];
                }
            }
            float ov[8];
            {
                const int q = 8 + (u & 7);
                #pragma unroll
                for (int i = 0; i < 4; ++i) {
                    ov[i]     = fs8[i]     * s_fsfd[(rb + i) * 20 + q];
                    ov[4 + i] = fs8[4 + i] * s_fsfd[(rb + 16 + i) * 20 + q];
                }
            }
            __builtin_amdgcn_s_setprio(1);
            #pragma unroll
            for (int t = 0; t < 3; ++t) {
                f32x4 D0 = {0.f, 0.f, 0.f, 0.f};
                f32x4 D1 = {0.f, 0.f, 0.f, 0.f};
                #pragma unroll
                for (int sl = 0; sl < 2; ++sl) {
                    const int fo = ((sl * 3 + t) * 2) * 512 + lane * 8;
                    s16x8 Bh = *reinterpret_cast<const s16x8*>(BB + fo);
                    s16x8 Bl = *reinterpret_cast<const s16x8*>(BB + fo + 512);
                    D0 = __builtin_amdgcn_mfma_f32_16x16x32_bf16(AhF[0][sl], Bh, D0, 0, 0, 0);
                    D0 = __builtin_amdgcn_mfma_f32_16x16x32_bf16(AhF[0][sl], Bl, D0, 0, 0, 0);
                    D0 = __builtin_amdgcn_mfma_f32_16x16x32_bf16(AlF[0][sl], Bh, D0, 0, 0, 0);
                    D1 = __builtin_amdgcn_mfma_f32_16x16x32_bf16(AhF[1][sl], Bh, D1, 0, 0, 0);
                    D1 = __builtin_amdgcn_mfma_f32_16x16x32_bf16(AhF[1][sl], Bl, D1, 0, 0, 0);
                    D1 = __builtin_amdgcn_mfma_f32_16x16x32_bf16(AlF[1][sl], Bh, D1, 0, 0, 0);
                }
                __builtin_amdgcn_s_setprio(0);
                #pragma unroll
                for (int i = 0; i < 4; ++i) {
                    acc[0][t][i] = fmaf(ov[i],     D0[i], acc[0][t][i]);
                    acc[1][t][i] = fmaf(ov[4 + i], D1[i], acc[1][t][i]);
                }
                __builtin_amdgcn_s_setprio(1);
            }
            __builtin_amdgcn_s_setprio(0);
        } else {
            // bias chunk: accumulate O-fragment products directly
            __builtin_amdgcn_s_setprio(1);
            #pragma unroll
            for (int t = 0; t < 3; ++t) {
                #pragma unroll
                for (int sl = 0; sl < 2; ++sl) {
                    const int fo = ((sl * 3 + t) * 2) * 512 + lane * 8;
                    s16x8 Bh = *reinterpret_cast<const s16x8*>(BB + fo);
                    s16x8 Bl = *reinterpret_cast<const s16x8*>(BB + fo + 512);
                    acc[0][t] = __builtin_amdgcn_mfma_f32_16x16x32_bf16(OhF[0][sl], Bh, acc[0][t], 0, 0, 0);
                    acc[0][t] = __builtin_amdgcn_mfma_f32_16x16x32_bf16(OhF[0][sl], Bl, acc[0][t], 0, 0, 0);
                    acc[0][t] = __builtin_amdgcn_mfma_f32_16x16x32_bf16(OlF[0][sl], Bh, acc[0][t], 0, 0, 0);
                    acc[1][t] = __builtin_amdgcn_mfma_f32_16x16x32_bf16(OhF[1][sl], Bh, acc[1][t], 0, 0, 0);
                    acc[1][t] = __builtin_amdgcn_mfma_f32_16x16x32_bf16(OhF[1][sl], Bl, acc[1][t], 0, 0, 0);
                    acc[1][t] = __builtin_amdgcn_mfma_f32_16x16x32_bf16(OlF[1][sl], Bh, acc[1][t], 0, 0, 0);
                }
            }
            __builtin_amdgcn_s_setprio(0);
        }
        if (u < 63) {
            asm volatile("s_waitcnt vmcnt(3) lgkmcnt(0)" ::: "memory");  // u+1 landed; u+2 flying
            __builtin_amdgcn_s_barrier();
            __builtin_amdgcn_sched_barrier(0);
        } else if (u < 64) {
            asm volatile("s_waitcnt vmcnt(0) lgkmcnt(0)" ::: "memory");  // drain bias chunk
            __builtin_amdgcn_s_barrier();
            __builtin_amdgcn_sched_barrier(0);
        }
        cur = (cur == 2) ? 0 : cur + 1;
    }
#undef ISSUE

    // ---- write m: D row = rb + i (edge), col = lane&15 (lo) ----
    #pragma unroll
    for (int mt = 0; mt < 2; ++mt) {
        #pragma unroll
        for (int t = 0; t < 3; ++t) {
            #pragma unroll
            for (int i = 0; i < 4; ++i) {
                const int ee = e0 + rb + mt * 16 + i;
                if (ee < E) ef[(size_t)ee * 52 + t * 16 + (lane & 15)] = acc[mt][t][i];
            }
        }
    }
}

// ---------------- kernel 4: gather-reduce per node ----------------
__global__ __launch_bounds__(256) void k_gather(const float* __restrict__ ef,
                                                const int* __restrict__ offs,
                                                const int* __restrict__ eidx,
                                                float* __restrict__ out, int N) {
    const int lane = threadIdx.x & 63;
    const int node = blockIdx.x * 4 + (threadIdx.x >> 6);
    if (node >= N) return;

    const int beg = offs[node];
    const int end = offs[node + 1];

    int mi[4], ii[4], jj[4], mode[4];
    #pragma unroll
    for (int t = 0; t < 4; ++t) {
        int c = lane + 64 * t;
        if (c < 16)       { mi[t] = c;                 ii[t] = 0;     jj[t] = 0;     mode[t] = 0; }
        else if (c < 64)  { int u = c - 16; mi[t] = 16 + u / 3; ii[t] = u % 3; jj[t] = 0; mode[t] = 1; }
        else if (c < 208) { int u = c - 64; mi[t] = 32 + u / 9; int rr = u % 9; ii[t] = rr / 3; jj[t] = rr % 3; mode[t] = 2; }
        else              { mi[t] = 0; ii[t] = 0; jj[t] = 0; mode[t] = 3; }
    }

    float acc[4] = {0.f, 0.f, 0.f, 0.f};
    #pragma unroll 4
    for (int k = beg; k < end; ++k) {
        const int e = eidx[k];
        const float* b = ef + (size_t)e * 52;
        float v = (lane < 51) ? b[lane] : 0.0f;
        float n0 = __shfl(v, 48);
        float n1 = __shfl(v, 49);
        float n2 = __shfl(v, 50);
        #pragma unroll
        for (int t = 0; t < 4; ++t) {
            float mval = __shfl(v, mi[t]);
            float ni = (ii[t] == 0) ? n0 : ((ii[t] == 1) ? n1 : n2);
            float nj = (jj[t] == 0) ? n0 : ((jj[t] == 1) ? n1 : n2);
            float f  = (mode[t] == 0) ? 1.0f
                     : (mode[t] == 1) ? ni
                     : (mode[t] == 2) ? ni * nj
                     : 0.0f;
            acc[t] = fmaf(mval, f, acc[t]);
        }
    }

    const float inv = 1.0f / fmaxf((float)(end - beg), 1.0f);
    float* op = out + (size_t)node * 208;
    op[lane]        = acc[0] * inv;
    op[lane + 64]   = acc[1] * inv;
    op[lane + 128]  = acc[2] * inv;
    if (lane < 16) op[lane + 192] = acc[3] * inv;
}

extern "C" void kernel_launch(void* const* d_in, const int* in_sizes, int n_in,
                              void* d_out, int out_size, void* d_ws, size_t ws_size,
                              hipStream_t stream) {
    const float* pos    = (const float*)d_in[0];
    const int*   A      = (const int*)d_in[1];
    const int*   batch  = (const int*)d_in[2];
    const int*   esrc   = (const int*)d_in[3];
    const int*   edst   = (const int*)d_in[4];
    const float* eshift = (const float*)d_in[5];
    const float* cell   = (const float*)d_in[6];
    const float* embt   = (const float*)d_in[7];
    const float* mw1    = (const float*)d_in[8];
    const float* mb1    = (const float*)d_in[9];
    const float* mw2    = (const float*)d_in[10];
    const float* mb2    = (const float*)d_in[11];
    const float* fw1    = (const float*)d_in[12];
    const float* fb1    = (const float*)d_in[13];
    const float* fw2    = (const float*)d_in[14];
    const float* fb2    = (const float*)d_in[15];
    const float* w3     = (const float*)d_in[16];
    const float* b3     = (const float*)d_in[17];
    float* out = (float*)d_out;

    const int N = in_sizes[1];
    const int E = in_sizes[3];

    char* p = (char*)d_ws;
    auto take = [&](size_t bytes) {
        char* q = p;
        p += (bytes + 255) & ~(size_t)255;
        return q;
    };
    ushort* wz    = (ushort*)take((size_t)130 * 3 * 2 * 512 * sizeof(ushort)); // ~780 KiB
    float* Ai     = (float*)take((size_t)N * 8 * sizeof(float));
    int*   deg    = (int*)  take((size_t)N * sizeof(int));
    int*   offs   = (int*)  take((size_t)(N + 1) * sizeof(int));
    int*   cursor = (int*)  take((size_t)N * sizeof(int));
    int*   eidx   = (int*)  take((size_t)E * sizeof(int));
    float* ef     = (float*)take((size_t)E * 52 * sizeof(float)); // ~20.8 MiB

    hipMemsetAsync(deg, 0, (size_t)N * sizeof(int), stream);

    const int aiB = (N + 255) / 256;
    const int histB = (E + 255) / 256;
    k_setup<<<780 + aiB + histB, 256, 0, stream>>>(w3, b3, wz, A, embt, mw1, mb1,
                                                   mw2, mb2, Ai, edst, deg, N, E, aiB);
    k_scan<<<1, 1024, 0, stream>>>(deg, offs, cursor, N);
    k_edge<<<(E + 127) / 128, 256, 0, stream>>>(pos, batch, esrc, edst, eshift, cell,
                                                fw1, fb1, fw2, fb2, wz, Ai,
                                                ef, cursor, eidx, E);
    k_gather<<<(N + 3) / 4, 256, 0, stream>>>(ef, offs, eidx, out, N);
}

// Round 12
// 245.891 us; speedup vs baseline: 1.1064x; 1.1064x over previous
//
#include <hip/hip_runtime.h>
#include <math.h>
#include <stdint.h>

// Shapes (fixed by the reference)
// N=10000, E=100000, G=64, NB=16, EMB=16, S=8, COUT=16, LMAX=2
// WNUM = 3*16*8*8 = 3072 ; ef width = 16 + 48 + 144 = 208
// Per-edge compact result: m[48] (l*16+o) + n[3], stored as 52 floats.
//
// Main contraction as a fused GEMM via MFMA:
//   m[e][lo] = sum_ab o[e][ab] * ( sum_c h[e][c] * w3[c][lo*64+ab] ) + bias
// Per K-chunk u (= one ab), MFMA computes D = (h . B_ab) with h split into
// bf16 hi+lo (3 products, fp32 accum); then acc += o[e][ab] * D in exact f32.
// B-fragments stream global->reg (depth-2 double buffer; depth-3 spills, r9;
// LDS-shared variants are slower, r6/r11). Per u: ONE MFMA cluster (36) into
// six static D accumulators, ONE result-wait, then the 24 o-scale fmafs --
// single latency exposure per u instead of three (r7 had 3x).

typedef float  f32x4  __attribute__((ext_vector_type(4)));
typedef short  s16x8  __attribute__((ext_vector_type(8)));
typedef __bf16 bf16x8 __attribute__((ext_vector_type(8)));

__device__ __forceinline__ float silu_f(float x) {
    return x / (1.0f + __expf(-x));
}

// split 8 f32 (two f32x4, k-local order j=0..7) into bf16 hi + lo fragments
__device__ __forceinline__ void split8(f32x4 a, f32x4 b, s16x8& hi, s16x8& lo) {
    bf16x8 h8, l8;
    #pragma unroll
    for (int i = 0; i < 4; ++i) {
        float z = a[i]; __bf16 zh = (__bf16)z; h8[i] = zh; l8[i] = (__bf16)(z - (float)zh);
        float y = b[i]; __bf16 yh = (__bf16)y; h8[4 + i] = yh; l8[4 + i] = (__bf16)(y - (float)yh);
    }
    hi = __builtin_bit_cast(s16x8, h8);
    lo = __builtin_bit_cast(s16x8, l8);
}

// ---------------- kernel 1 (fused setup): prep wz | node Ai | edge_dst hist ----------------
// K-step s (0..129): 32 k-values. s<128: ab=s>>1, c=(s&1)*32+kl. s>=128: ab=(s-128)*32+kl.
// Fragment lane l: col lo = t*16 + (l&15); kl = (l>>4)*8 + j.
// wz[ ((s*3 + t)*2 + plane)*512 + l*8 + j ]  (ushort bf16)
__global__ __launch_bounds__(256) void k_setup(const float* __restrict__ w3,
                                               const float* __restrict__ b3,
                                               ushort* __restrict__ wz,
                                               const int* __restrict__ A,
                                               const float* __restrict__ embt,
                                               const float* __restrict__ w1,
                                               const float* __restrict__ b1,
                                               const float* __restrict__ w2,
                                               const float* __restrict__ b2,
                                               float* __restrict__ Ai,
                                               const int* __restrict__ edst,
                                               int* __restrict__ deg,
                                               int N, int E, int aiB) {
    const int b = blockIdx.x;
    const int tid = threadIdx.x;
    if (b < 780) {                         // ---- prep: 780*256 = 199680 = 130*3*512
        int t = b * 256 + tid;
        int j    = t & 7;
        int l    = (t >> 3) & 63;
        int rest = t >> 9;          // s*3 + tt
        int tt   = rest % 3;
        int s    = rest / 3;
        int lo   = tt * 16 + (l & 15);
        int kl   = (l >> 4) * 8 + j;
        float v;
        if (s < 128) {
            int ab = s >> 1;
            int c  = (s & 1) * 32 + kl;
            v = w3[c * 3072 + lo * 64 + ab];
        } else {
            int ab = (s - 128) * 32 + kl;
            v = b3[lo * 64 + ab];
        }
        __bf16 hi  = (__bf16)v;
        __bf16 lor = (__bf16)(v - (float)hi);
        size_t base = (size_t)(s * 3 + tt) * 2 * 512 + l * 8 + j;
        wz[base]       = __builtin_bit_cast(ushort, hi);
        wz[base + 512] = __builtin_bit_cast(ushort, lor);
    } else if (b < 780 + aiB) {            // ---- node Ai
        int i = (b - 780) * 256 + tid;
        if (i >= N) return;
        float e[16];
        const float* er = embt + A[i] * 16;
        #pragma unroll
        for (int k = 0; k < 16; ++k) e[k] = er[k];
        float h1[64];
        #pragma unroll
        for (int j = 0; j < 64; ++j) {
            float a = b1[j];
            #pragma unroll
            for (int k = 0; k < 16; ++k) a = fmaf(e[k], w1[k * 64 + j], a);
            h1[j] = silu_f(a);
        }
        #pragma unroll
        for (int o = 0; o < 8; ++o) {
            float a = b2[o];
            #pragma unroll
            for (int j = 0; j < 64; ++j) a = fmaf(h1[j], w2[j * 8 + o], a);
            Ai[i * 8 + o] = a;
        }
    } else {                               // ---- histogram of edge_dst
        int e = (b - 780 - aiB) * 256 + tid;
        if (e < E) atomicAdd(&deg[edst[e]], 1);
    }
}

// ---------------- kernel 2: single-block exclusive scan (N=10000), 1024 threads ----------------
__global__ __launch_bounds__(1024) void k_scan(const int* __restrict__ deg,
                                               int* __restrict__ offs,
                                               int* __restrict__ cursor, int N) {
    __shared__ int part[1024];
    const int t = threadIdx.x;
    const int chunk = (N + 1023) / 1024;
    const int beg = t * chunk;
    const int end = min(beg + chunk, N);
    int s = 0;
    for (int i = beg; i < end; ++i) s += deg[i];
    part[t] = s;
    __syncthreads();
    for (int off = 1; off < 1024; off <<= 1) {
        int v = (t >= off) ? part[t - off] : 0;
        __syncthreads();
        part[t] += v;
        __syncthreads();
    }
    int run = (t == 0) ? 0 : part[t - 1];
    for (int i = beg; i < end; ++i) {
        offs[i] = run;
        cursor[i] = run;
        run += deg[i];
    }
    if (t == 1023) offs[N] = part[1023];
}

// ---------------- kernel 3: per-edge compute via MFMA ----------------
// Block = 256 threads = 4 waves = 128 edges (M=32 per wave: 2 x 16-row tiles).
// Front end (verified) runs twice (rows 0-63, 64-127); h moves to per-lane
// bf16 hi/lo fragments (registers). Main K-loop: BARRIER-FREE -- B fragments
// in a depth-2 register double buffer, L1/L2-shared across waves.
__global__ __launch_bounds__(256, 2) void k_edge(
    const float* __restrict__ pos, const int* __restrict__ batch,
    const int* __restrict__ esrc, const int* __restrict__ edst,
    const float* __restrict__ eshift, const float* __restrict__ cell,
    const float* __restrict__ fw1, const float* __restrict__ fb1,
    const float* __restrict__ fw2, const float* __restrict__ fb2,
    const ushort* __restrict__ wz,
    const float* __restrict__ Ai, float* __restrict__ ef,
    int* __restrict__ cursor, int* __restrict__ eidx, int E) {

    __shared__ __align__(16) float s_un[8704];   // h1 (stride 65) -> h (stride 68)
    __shared__ __align__(16) float s_o[8704];    // o[128 edges][68-stride]

    const int tid  = threadIdx.x;
    const int lane = tid & 63;
    const int w    = __builtin_amdgcn_readfirstlane(tid >> 6);   // wave id
    const int e0   = blockIdx.x * 128;
    const int j0   = w * 16;                                     // c-chunk

    const f32x4* wzv = reinterpret_cast<const f32x4*>(wz);

    // B-fragment load: 12 x 16B per lane, chunk U (perfectly coalesced, L1-shared)
    s16x8 Ba[12], Bb[12];
#define LOADB(ARR, U) { \
    const f32x4* gs = wzv + (size_t)(U) * 768 + lane; \
    _Pragma("unroll") \
    for (int f = 0; f < 12; ++f) ARR[f] = __builtin_bit_cast(s16x8, gs[f * 64]); }

    LOADB(Ba, 0);   // prologue: chunk 0 in flight across the whole front end

    // ---- front end, two rounds of 64 edges ----
    #pragma unroll
    for (int rr = 0; rr < 2; ++rr) {
        const int e = e0 + rr * 64 + lane;
        const bool valid = (e < E);
        const int ec = valid ? e : (E - 1);
        const int src = esrc[ec];
        const int dst = edst[ec];

        const int g0 = batch[src];
        const float s0 = eshift[ec * 3 + 0], s1 = eshift[ec * 3 + 1], s2 = eshift[ec * 3 + 2];
        const float* cl = cell + g0 * 9;
        float vx = pos[dst * 3 + 0] - pos[src * 3 + 0] + s0 * cl[0] + s1 * cl[3] + s2 * cl[6];
        float vy = pos[dst * 3 + 1] - pos[src * 3 + 1] + s0 * cl[1] + s1 * cl[4] + s2 * cl[7];
        float vz = pos[dst * 3 + 2] - pos[src * 3 + 2] + s0 * cl[2] + s1 * cl[5] + s2 * cl[8];
        float r = sqrtf(vx * vx + vy * vy + vz * vz);
        float rinv = 1.0f / fmaxf(r, 1e-9f);
        float nx = vx * rinv, ny = vy * rinv, nz = vz * rinv;

        float embv[16];
        const float step = 4.0f / 17.0f;
        const float sc = 4.0f / 1.12f;
        #pragma unroll
        for (int k = 0; k < 16; ++k) {
            float d = (r - (float)(k + 1) * step) / step;
            embv[k] = __expf(-d * d) * sc;
        }

        // h1 chunk -> s_un (stride 65)
        const int hb = (rr * 64 + lane) * 65;
        #pragma unroll
        for (int jj = 0; jj < 16; ++jj) {
            const int j = j0 + jj;
            float a = fb1[j];
            #pragma unroll
            for (int k = 0; k < 16; ++k) a = fmaf(embv[k], fw1[k * 64 + j], a);
            s_un[hb + j] = silu_f(a);
        }

        // o chunk -> s_o (stride 68)
        {
            const float* As = Ai + (size_t)src * 8;
            const float* Ad = Ai + (size_t)dst * 8;
            float fsa0 = As[2 * w], fsa1 = As[2 * w + 1];
            f32x4 d0 = *reinterpret_cast<const f32x4*>(Ad);
            f32x4 d1 = *reinterpret_cast<const f32x4*>(Ad + 4);
            float fdv[8] = {d0[0], d0[1], d0[2], d0[3], d1[0], d1[1], d1[2], d1[3]};
            const int ob = (rr * 64 + lane) * 68 + j0;
            #pragma unroll
            for (int i = 0; i < 8; ++i)  s_o[ob + i]     = fsa0 * fdv[i];
            #pragma unroll
            for (int i = 0; i < 8; ++i)  s_o[ob + 8 + i] = fsa1 * fdv[i];
        }

        // n + CSR scatter (one thread per edge)
        if (w == 0 && valid) {
            float* np = ef + (size_t)e * 52;
            np[48] = nx; np[49] = ny; np[50] = nz;
            int pp = atomicAdd(&cursor[dst], 1);
            eidx[pp] = e;
        }
    }
    __syncthreads();

    // ---- hc chunks (registers) for both rounds ----
    float hcr[2][16];
    #pragma unroll
    for (int rr = 0; rr < 2; ++rr) {
        const int hb = (rr * 64 + lane) * 65;
        #pragma unroll
        for (int i = 0; i < 16; ++i) hcr[rr][i] = fb2[j0 + i];
        #pragma unroll 4
        for (int j = 0; j < 64; ++j) {
            const float v = s_un[hb + j];
            const float* w2r = fw2 + j * 64 + j0;   // wave-uniform -> scalar
            #pragma unroll
            for (int i = 0; i < 16; ++i) hcr[rr][i] = fmaf(v, w2r[i], hcr[rr][i]);
        }
        #pragma unroll
        for (int i = 0; i < 16; ++i) hcr[rr][i] = silu_f(hcr[rr][i]);
    }
    __syncthreads();   // all h1 reads done -> rewrite region at stride 68

    #pragma unroll
    for (int rr = 0; rr < 2; ++rr) {
        const int hb = (rr * 64 + lane) * 68 + j0;
        #pragma unroll
        for (int i = 0; i < 16; ++i) s_un[hb + i] = hcr[rr][i];
    }
    __syncthreads();

    LOADB(Bb, 64);   // bias chunk in flight across fragment extraction

    // ---- extract per-lane A (h) and O (bias) fragments ----
    const int g = lane >> 4;                 // k-group
    const int mrow = w * 32 + (lane & 15);   // M-tile 0 row
    s16x8 AhF[2][2], AlF[2][2], OhF[2][2], OlF[2][2];
    #pragma unroll
    for (int mt = 0; mt < 2; ++mt) {
        const float* hr = s_un + (mrow + mt * 16) * 68;
        const float* orw = s_o + (mrow + mt * 16) * 68;
        f32x4 a0 = *reinterpret_cast<const f32x4*>(hr + g * 8);
        f32x4 a1 = *reinterpret_cast<const f32x4*>(hr + g * 8 + 4);
        split8(a0, a1, AhF[mt][0], AlF[mt][0]);
        f32x4 a2 = *reinterpret_cast<const f32x4*>(hr + 32 + g * 8);
        f32x4 a3 = *reinterpret_cast<const f32x4*>(hr + 32 + g * 8 + 4);
        split8(a2, a3, AhF[mt][1], AlF[mt][1]);
        f32x4 o0 = *reinterpret_cast<const f32x4*>(orw + g * 8);
        f32x4 o1 = *reinterpret_cast<const f32x4*>(orw + g * 8 + 4);
        split8(o0, o1, OhF[mt][0], OlF[mt][0]);
        f32x4 o2 = *reinterpret_cast<const f32x4*>(orw + 32 + g * 8);
        f32x4 o3 = *reinterpret_cast<const f32x4*>(orw + 32 + g * 8 + 4);
        split8(o2, o3, OhF[mt][1], OlF[mt][1]);
    }

    const int rb = w * 32 + (lane >> 4) * 4;   // first output row of this lane's D

    f32x4 acc[2][3];
    #pragma unroll
    for (int mt = 0; mt < 2; ++mt)
        #pragma unroll
        for (int t = 0; t < 3; ++t) acc[mt][t] = (f32x4){0.f, 0.f, 0.f, 0.f};

    // ---- bias tail FIRST (frees O-fragments before the main loop) ----
    __builtin_amdgcn_s_setprio(1);
    #pragma unroll
    for (int t = 0; t < 3; ++t) {
        #pragma unroll
        for (int sl = 0; sl < 2; ++sl) {
            s16x8 Bh = Bb[(sl * 3 + t) * 2];
            s16x8 Bl = Bb[(sl * 3 + t) * 2 + 1];
            acc[0][t] = __builtin_amdgcn_mfma_f32_16x16x32_bf16(OhF[0][sl], Bh, acc[0][t], 0, 0, 0);
            acc[0][t] = __builtin_amdgcn_mfma_f32_16x16x32_bf16(OhF[0][sl], Bl, acc[0][t], 0, 0, 0);
            acc[0][t] = __builtin_amdgcn_mfma_f32_16x16x32_bf16(OlF[0][sl], Bh, acc[0][t], 0, 0, 0);
            acc[1][t] = __builtin_amdgcn_mfma_f32_16x16x32_bf16(OhF[1][sl], Bh, acc[1][t], 0, 0, 0);
            acc[1][t] = __builtin_amdgcn_mfma_f32_16x16x32_bf16(OhF[1][sl], Bl, acc[1][t], 0, 0, 0);
            acc[1][t] = __builtin_amdgcn_mfma_f32_16x16x32_bf16(OlF[1][sl], Bh, acc[1][t], 0, 0, 0);
        }
    }
    __builtin_amdgcn_s_setprio(0);

    // ---- main K-loop: barrier-free, register double buffer, unroll x2 ----
    // Per u: ONE 36-MFMA cluster into six STATIC D accumulators, one result
    // wait, then all 24 o-scale fmafs (r7 exposed the MFMA latency 3x/u).
#define MSTEP(BC, U) { \
    float ov[8]; \
    _Pragma("unroll") \
    for (int i = 0; i < 4; ++i) { \
        ov[i]     = s_o[(rb + i) * 68 + (U)]; \
        ov[4 + i] = s_o[(rb + 16 + i) * 68 + (U)]; \
    } \
    f32x4 D0 = {0.f, 0.f, 0.f, 0.f}, D1 = {0.f, 0.f, 0.f, 0.f}; \
    f32x4 D2 = {0.f, 0.f, 0.f, 0.f}, D3 = {0.f, 0.f, 0.f, 0.f}; \
    f32x4 D4 = {0.f, 0.f, 0.f, 0.f}, D5 = {0.f, 0.f, 0.f, 0.f}; \
    __builtin_amdgcn_s_setprio(1); \
    _Pragma("unroll") \
    for (int sl = 0; sl < 2; ++sl) { \
        s16x8 Bh0 = BC[(sl * 3 + 0) * 2], Bl0 = BC[(sl * 3 + 0) * 2 + 1]; \
        s16x8 Bh1 = BC[(sl * 3 + 1) * 2], Bl1 = BC[(sl * 3 + 1) * 2 + 1]; \
        s16x8 Bh2 = BC[(sl * 3 + 2) * 2], Bl2 = BC[(sl * 3 + 2) * 2 + 1]; \
        D0 = __builtin_amdgcn_mfma_f32_16x16x32_bf16(AhF[0][sl], Bh0, D0, 0, 0, 0); \
        D1 = __builtin_amdgcn_mfma_f32_16x16x32_bf16(AhF[1][sl], Bh0, D1, 0, 0, 0); \
        D2 = __builtin_amdgcn_mfma_f32_16x16x32_bf16(AhF[0][sl], Bh1, D2, 0, 0, 0); \
        D3 = __builtin_amdgcn_mfma_f32_16x16x32_bf16(AhF[1][sl], Bh1, D3, 0, 0, 0); \
        D4 = __builtin_amdgcn_mfma_f32_16x16x32_bf16(AhF[0][sl], Bh2, D4, 0, 0, 0); \
        D5 = __builtin_amdgcn_mfma_f32_16x16x32_bf16(AhF[1][sl], Bh2, D5, 0, 0, 0); \
        D0 = __builtin_amdgcn_mfma_f32_16x16x32_bf16(AlF[0][sl], Bh0, D0, 0, 0, 0); \
        D1 = __builtin_amdgcn_mfma_f32_16x16x32_bf16(AlF[1][sl], Bh0, D1, 0, 0, 0); \
        D2 = __builtin_amdgcn_mfma_f32_16x16x32_bf16(AlF[0][sl], Bh1, D2, 0, 0, 0); \
        D3 = __builtin_amdgcn_mfma_f32_16x16x32_bf16(AlF[1][sl], Bh1, D3, 0, 0, 0); \
        D4 = __builtin_amdgcn_mfma_f32_16x16x32_bf16(AlF[0][sl], Bh2, D4, 0, 0, 0); \
        D5 = __builtin_amdgcn_mfma_f32_16x16x32_bf16(AlF[1][sl], Bh2, D5, 0, 0, 0); \
        D0 = __builtin_amdgcn_mfma_f32_16x16x32_bf16(AhF[0][sl], Bl0, D0, 0, 0, 0); \
        D1 = __builtin_amdgcn_mfma_f32_16x16x32_bf16(AhF[1][sl], Bl0, D1, 0, 0, 0); \
        D2 = __builtin_amdgcn_mfma_f32_16x16x32_bf16(AhF[0][sl], Bl1, D2, 0, 0, 0); \
        D3 = __builtin_amdgcn_mfma_f32_16x16x32_bf16(AhF[1][sl], Bl1, D3, 0, 0, 0); \
        D4 = __builtin_amdgcn_mfma_f32_16x16x32_bf16(AhF[0][sl], Bl2, D4, 0, 0, 0); \
        D5 = __builtin_amdgcn_mfma_f32_16x16x32_bf16(AhF[1][sl], Bl2, D5, 0, 0, 0); \
    } \
    __builtin_amdgcn_s_setprio(0); \
    _Pragma("unroll") \
    for (int i = 0; i < 4; ++i) { \
        acc[0][0][i] = fmaf(ov[i],     D0[i], acc[0][0][i]); \
        acc[1][0][i] = fmaf(ov[4 + i], D1[i], acc[1][0][i]); \
        acc[0][1][i] = fmaf(ov[i],     D2[i], acc[0][1][i]); \
        acc[1][1][i] = fmaf(ov[4 + i], D3[i], acc[1][1][i]); \
        acc[0][2][i] = fmaf(ov[i],     D4[i], acc[0][2][i]); \
        acc[1][2][i] = fmaf(ov[4 + i], D5[i], acc[1][2][i]); \
    } }

    for (int u = 0; u < 64; u += 2) {
        LOADB(Bb, u + 1);
        MSTEP(Ba, u);
        if (u + 2 < 64) LOADB(Ba, u + 2);
        MSTEP(Bb, u + 1);
    }
#undef MSTEP
#undef LOADB

    // ---- write m: D row = rb + i (edge), col = lane&15 (lo) ----
    #pragma unroll
    for (int mt = 0; mt < 2; ++mt) {
        #pragma unroll
        for (int t = 0; t < 3; ++t) {
            #pragma unroll
            for (int i = 0; i < 4; ++i) {
                const int ee = e0 + rb + mt * 16 + i;
                if (ee < E) ef[(size_t)ee * 52 + t * 16 + (lane & 15)] = acc[mt][t][i];
            }
        }
    }
}

// ---------------- kernel 4: gather-reduce per node ----------------
__global__ __launch_bounds__(256) void k_gather(const float* __restrict__ ef,
                                                const int* __restrict__ offs,
                                                const int* __restrict__ eidx,
                                                float* __restrict__ out, int N) {
    const int lane = threadIdx.x & 63;
    const int node = blockIdx.x * 4 + (threadIdx.x >> 6);
    if (node >= N) return;

    const int beg = offs[node];
    const int end = offs[node + 1];

    int mi[4], ii[4], jj[4], mode[4];
    #pragma unroll
    for (int t = 0; t < 4; ++t) {
        int c = lane + 64 * t;
        if (c < 16)       { mi[t] = c;                 ii[t] = 0;     jj[t] = 0;     mode[t] = 0; }
        else if (c < 64)  { int u = c - 16; mi[t] = 16 + u / 3; ii[t] = u % 3; jj[t] = 0; mode[t] = 1; }
        else if (c < 208) { int u = c - 64; mi[t] = 32 + u / 9; int rr = u % 9; ii[t] = rr / 3; jj[t] = rr % 3; mode[t] = 2; }
        else              { mi[t] = 0; ii[t] = 0; jj[t] = 0; mode[t] = 3; }
    }

    float acc[4] = {0.f, 0.f, 0.f, 0.f};
    #pragma unroll 4
    for (int k = beg; k < end; ++k) {
        const int e = eidx[k];
        const float* b = ef + (size_t)e * 52;
        float v = (lane < 51) ? b[lane] : 0.0f;
        float n0 = __shfl(v, 48);
        float n1 = __shfl(v, 49);
        float n2 = __shfl(v, 50);
        #pragma unroll
        for (int t = 0; t < 4; ++t) {
            float mval = __shfl(v, mi[t]);
            float ni = (ii[t] == 0) ? n0 : ((ii[t] == 1) ? n1 : n2);
            float nj = (jj[t] == 0) ? n0 : ((jj[t] == 1) ? n1 : n2);
            float f  = (mode[t] == 0) ? 1.0f
                     : (mode[t] == 1) ? ni
                     : (mode[t] == 2) ? ni * nj
                     : 0.0f;
            acc[t] = fmaf(mval, f, acc[t]);
        }
    }

    const float inv = 1.0f / fmaxf((float)(end - beg), 1.0f);
    float* op = out + (size_t)node * 208;
    op[lane]        = acc[0] * inv;
    op[lane + 64]   = acc[1] * inv;
    op[lane + 128]  = acc[2] * inv;
    if (lane < 16) op[lane + 192] = acc[3] * inv;
}

extern "C" void kernel_launch(void* const* d_in, const int* in_sizes, int n_in,
                              void* d_out, int out_size, void* d_ws, size_t ws_size,
                              hipStream_t stream) {
    const float* pos    = (const float*)d_in[0];
    const int*   A      = (const int*)d_in[1];
    const int*   batch  = (const int*)d_in[2];
    const int*   esrc   = (const int*)d_in[3];
    const int*   edst   = (const int*)d_in[4];
    const float* eshift = (const float*)d_in[5];
    const float* cell   = (const float*)d_in[6];
    const float* embt   = (const float*)d_in[7];
    const float* mw1    = (const float*)d_in[8];
    const float* mb1    = (const float*)d_in[9];
    const float* mw2    = (const float*)d_in[10];
    const float* mb2    = (const float*)d_in[11];
    const float* fw1    = (const float*)d_in[12];
    const float* fb1    = (const float*)d_in[13];
    const float* fw2    = (const float*)d_in[14];
    const float* fb2    = (const float*)d_in[15];
    const float* w3     = (const float*)d_in[16];
    const float* b3     = (const float*)d_in[17];
    float* out = (float*)d_out;

    const int N = in_sizes[1];
    const int E = in_sizes[3];

    char* p = (char*)d_ws;
    auto take = [&](size_t bytes) {
        char* q = p;
        p += (bytes + 255) & ~(size_t)255;
        return q;
    };
    ushort* wz    = (ushort*)take((size_t)130 * 3 * 2 * 512 * sizeof(ushort)); // ~780 KiB
    float* Ai     = (float*)take((size_t)N * 8 * sizeof(float));
    int*   deg    = (int*)  take((size_t)N * sizeof(int));
    int*   offs   = (int*)  take((size_t)(N + 1) * sizeof(int));
    int*   cursor = (int*)  take((size_t)N * sizeof(int));
    int*   eidx   = (int*)  take((size_t)E * sizeof(int));
    float* ef     = (float*)take((size_t)E * 52 * sizeof(float)); // ~20.8 MiB

    hipMemsetAsync(deg, 0, (size_t)N * sizeof(int), stream);

    const int aiB = (N + 255) / 256;
    const int histB = (E + 255) / 256;
    k_setup<<<780 + aiB + histB, 256, 0, stream>>>(w3, b3, wz, A, embt, mw1, mb1,
                                                   mw2, mb2, Ai, edst, deg, N, E, aiB);
    k_scan<<<1, 1024, 0, stream>>>(deg, offs, cursor, N);
    k_edge<<<(E + 127) / 128, 256, 0, stream>>>(pos, batch, esrc, edst, eshift, cell,
                                                fw1, fb1, fw2, fb2, wz, Ai,
                                                ef, cursor, eidx, E);
    k_gather<<<(N + 3) / 4, 256, 0, stream>>>(ef, offs, eidx, out, N);
}

// Round 13
// 237.546 us; speedup vs baseline: 1.1452x; 1.0351x over previous
//
#include <hip/hip_runtime.h>
#include <math.h>
#include <stdint.h>

// Shapes (fixed by the reference)
// N=10000, E=100000, G=64, NB=16, EMB=16, S=8, COUT=16, LMAX=2
// WNUM = 3*16*8*8 = 3072 ; ef width = 16 + 48 + 144 = 208
// Per-edge compact result: m[48] (l*16+o) + n[3], stored as 52 floats,
// written in CSR ORDER (slot = pos[e]) so k_gather reads are streaming.
//
// Main contraction as a fused GEMM via MFMA:
//   m[e][lo] = sum_ab o[e][ab] * ( sum_c h[e][c] * w3[c][lo*64+ab] ) + bias
// Per K-chunk u (= one ab), MFMA computes D = (h . B_ab) with h split into
// bf16 hi+lo (3 products, fp32 accum); then acc += o[e][ab] * D in exact f32.
// B-fragments stream global->reg (depth-2 double buffer; depth-3 spills, r9;
// LDS-shared variants are slower, r6/r11).

typedef float  f32x4  __attribute__((ext_vector_type(4)));
typedef short  s16x8  __attribute__((ext_vector_type(8)));
typedef __bf16 bf16x8 __attribute__((ext_vector_type(8)));

__device__ __forceinline__ float silu_f(float x) {
    return x / (1.0f + __expf(-x));
}

// split 8 f32 (two f32x4, k-local order j=0..7) into bf16 hi + lo fragments
__device__ __forceinline__ void split8(f32x4 a, f32x4 b, s16x8& hi, s16x8& lo) {
    bf16x8 h8, l8;
    #pragma unroll
    for (int i = 0; i < 4; ++i) {
        float z = a[i]; __bf16 zh = (__bf16)z; h8[i] = zh; l8[i] = (__bf16)(z - (float)zh);
        float y = b[i]; __bf16 yh = (__bf16)y; h8[4 + i] = yh; l8[4 + i] = (__bf16)(y - (float)yh);
    }
    hi = __builtin_bit_cast(s16x8, h8);
    lo = __builtin_bit_cast(s16x8, l8);
}

// ---------------- kernel 1 (fused setup): prep wz | node Ai | edge_dst hist ----------------
// wz layout (verified r5-r12): wz[((s*3+tt)*2+plane)*512 + l*8 + j], where
// s<128: ab=s>>1, c=(s&1)*32+kl ; s>=128: ab=(s-128)*32+kl ; kl=(l>>4)*8+j ;
// lo = tt*16 + (l&15).
// This round the prep loop enumerates w3 LINEARLY (lanes vary ab -> coalesced
// reads) and computes the scattered wz index by the exact inverse map:
//   s=(ab<<1)|(c>>5), kl=c&31, j=kl&7, l=((kl>>3)<<4)|(lo&15), tt=lo>>4.
__global__ __launch_bounds__(256) void k_setup(const float* __restrict__ w3,
                                               const float* __restrict__ b3,
                                               ushort* __restrict__ wz,
                                               const int* __restrict__ A,
                                               const float* __restrict__ embt,
                                               const float* __restrict__ w1,
                                               const float* __restrict__ b1,
                                               const float* __restrict__ w2,
                                               const float* __restrict__ b2,
                                               float* __restrict__ Ai,
                                               const int* __restrict__ edst,
                                               int* __restrict__ deg,
                                               int N, int E, int aiB) {
    const int b = blockIdx.x;
    const int tid = threadIdx.x;
    if (b < 768) {                         // ---- w3 prep: 768*256 = 196608 = 64*48*64
        const int idx = b * 256 + tid;     // idx = c*3072 + lo*64 + ab (linear in w3)
        const int c   = idx / 3072;
        const int rem = idx - c * 3072;
        const int lo  = rem >> 6;
        const int ab  = rem & 63;
        const float v = w3[idx];           // coalesced
        const int s  = (ab << 1) | (c >> 5);
        const int kl = c & 31;
        const int j  = kl & 7;
        const int l  = ((kl >> 3) << 4) | (lo & 15);
        const int tt = lo >> 4;
        __bf16 hi  = (__bf16)v;
        __bf16 lor = (__bf16)(v - (float)hi);
        const size_t base = (size_t)(s * 3 + tt) * 2 * 512 + l * 8 + j;
        wz[base]       = __builtin_bit_cast(ushort, hi);
        wz[base + 512] = __builtin_bit_cast(ushort, lor);
    } else if (b < 780) {                  // ---- bias prep: 12*256 = 3072 = 48*64
        const int i2 = (b - 768) * 256 + tid;   // i2 = lo*64 + ab (linear in b3)
        const int lo = i2 >> 6;
        const int ab = i2 & 63;
        const float v = b3[i2];            // coalesced
        const int s  = 128 + (ab >> 5);
        const int kl = ab & 31;
        const int j  = kl & 7;
        const int l  = ((kl >> 3) << 4) | (lo & 15);
        const int tt = lo >> 4;
        __bf16 hi  = (__bf16)v;
        __bf16 lor = (__bf16)(v - (float)hi);
        const size_t base = (size_t)(s * 3 + tt) * 2 * 512 + l * 8 + j;
        wz[base]       = __builtin_bit_cast(ushort, hi);
        wz[base + 512] = __builtin_bit_cast(ushort, lor);
    } else if (b < 780 + aiB) {            // ---- node Ai
        int i = (b - 780) * 256 + tid;
        if (i >= N) return;
        float e[16];
        const float* er = embt + A[i] * 16;
        #pragma unroll
        for (int k = 0; k < 16; ++k) e[k] = er[k];
        float h1[64];
        #pragma unroll
        for (int j = 0; j < 64; ++j) {
            float a = b1[j];
            #pragma unroll
            for (int k = 0; k < 16; ++k) a = fmaf(e[k], w1[k * 64 + j], a);
            h1[j] = silu_f(a);
        }
        #pragma unroll
        for (int o = 0; o < 8; ++o) {
            float a = b2[o];
            #pragma unroll
            for (int j = 0; j < 64; ++j) a = fmaf(h1[j], w2[j * 8 + o], a);
            Ai[i * 8 + o] = a;
        }
    } else {                               // ---- histogram of edge_dst
        int e = (b - 780 - aiB) * 256 + tid;
        if (e < E) atomicAdd(&deg[edst[e]], 1);
    }
}

// ---------------- kernel 2: single-block exclusive scan (N=10000), 1024 threads ----------------
__global__ __launch_bounds__(1024) void k_scan(const int* __restrict__ deg,
                                               int* __restrict__ offs,
                                               int* __restrict__ cursor, int N) {
    __shared__ int part[1024];
    const int t = threadIdx.x;
    const int chunk = (N + 1023) / 1024;
    const int beg = t * chunk;
    const int end = min(beg + chunk, N);
    int s = 0;
    for (int i = beg; i < end; ++i) s += deg[i];
    part[t] = s;
    __syncthreads();
    for (int off = 1; off < 1024; off <<= 1) {
        int v = (t >= off) ? part[t - off] : 0;
        __syncthreads();
        part[t] += v;
        __syncthreads();
    }
    int run = (t == 0) ? 0 : part[t - 1];
    for (int i = beg; i < end; ++i) {
        offs[i] = run;
        cursor[i] = run;
        run += deg[i];
    }
    if (t == 1023) offs[N] = part[1023];
}

// ---------------- kernel 3: per-edge compute via MFMA ----------------
// Block = 256 threads = 4 waves = 128 edges (M=32 per wave: 2 x 16-row tiles).
// Front end (verified) runs twice (rows 0-63, 64-127); h moves to per-lane
// bf16 hi/lo fragments (registers). Main K-loop: BARRIER-FREE -- B fragments
// in a depth-2 register double buffer, L1/L2-shared across waves.
// ef writes go to CSR slot s_pos[row] (block-local LDS) -> k_gather streams.
__global__ __launch_bounds__(256, 2) void k_edge(
    const float* __restrict__ pos, const int* __restrict__ batch,
    const int* __restrict__ esrc, const int* __restrict__ edst,
    const float* __restrict__ eshift, const float* __restrict__ cell,
    const float* __restrict__ fw1, const float* __restrict__ fb1,
    const float* __restrict__ fw2, const float* __restrict__ fb2,
    const ushort* __restrict__ wz,
    const float* __restrict__ Ai, float* __restrict__ ef,
    int* __restrict__ cursor, int E) {

    __shared__ __align__(16) float s_un[8704];   // h1 (stride 65) -> h (stride 68)
    __shared__ __align__(16) float s_o[8704];    // o[128 edges][68-stride]
    __shared__ int s_pos[128];                   // CSR slot per block-local edge

    const int tid  = threadIdx.x;
    const int lane = tid & 63;
    const int w    = __builtin_amdgcn_readfirstlane(tid >> 6);   // wave id
    const int e0   = blockIdx.x * 128;
    const int j0   = w * 16;                                     // c-chunk

    const f32x4* wzv = reinterpret_cast<const f32x4*>(wz);

    // B-fragment load: 12 x 16B per lane, chunk U (perfectly coalesced, L1-shared)
    s16x8 Ba[12], Bb[12];
#define LOADB(ARR, U) { \
    const f32x4* gs = wzv + (size_t)(U) * 768 + lane; \
    _Pragma("unroll") \
    for (int f = 0; f < 12; ++f) ARR[f] = __builtin_bit_cast(s16x8, gs[f * 64]); }

    LOADB(Ba, 0);   // prologue: chunk 0 in flight across the whole front end

    // ---- front end, two rounds of 64 edges ----
    #pragma unroll
    for (int rr = 0; rr < 2; ++rr) {
        const int e = e0 + rr * 64 + lane;
        const bool valid = (e < E);
        const int ec = valid ? e : (E - 1);
        const int src = esrc[ec];
        const int dst = edst[ec];

        const int g0 = batch[src];
        const float s0 = eshift[ec * 3 + 0], s1 = eshift[ec * 3 + 1], s2 = eshift[ec * 3 + 2];
        const float* cl = cell + g0 * 9;
        float vx = pos[dst * 3 + 0] - pos[src * 3 + 0] + s0 * cl[0] + s1 * cl[3] + s2 * cl[6];
        float vy = pos[dst * 3 + 1] - pos[src * 3 + 1] + s0 * cl[1] + s1 * cl[4] + s2 * cl[7];
        float vz = pos[dst * 3 + 2] - pos[src * 3 + 2] + s0 * cl[2] + s1 * cl[5] + s2 * cl[8];
        float r = sqrtf(vx * vx + vy * vy + vz * vz);
        float rinv = 1.0f / fmaxf(r, 1e-9f);
        float nx = vx * rinv, ny = vy * rinv, nz = vz * rinv;

        float embv[16];
        const float step = 4.0f / 17.0f;
        const float sc = 4.0f / 1.12f;
        #pragma unroll
        for (int k = 0; k < 16; ++k) {
            float d = (r - (float)(k + 1) * step) / step;
            embv[k] = __expf(-d * d) * sc;
        }

        // h1 chunk -> s_un (stride 65)
        const int hb = (rr * 64 + lane) * 65;
        #pragma unroll
        for (int jj = 0; jj < 16; ++jj) {
            const int j = j0 + jj;
            float a = fb1[j];
            #pragma unroll
            for (int k = 0; k < 16; ++k) a = fmaf(embv[k], fw1[k * 64 + j], a);
            s_un[hb + j] = silu_f(a);
        }

        // o chunk -> s_o (stride 68)
        {
            const float* As = Ai + (size_t)src * 8;
            const float* Ad = Ai + (size_t)dst * 8;
            float fsa0 = As[2 * w], fsa1 = As[2 * w + 1];
            f32x4 d0 = *reinterpret_cast<const f32x4*>(Ad);
            f32x4 d1 = *reinterpret_cast<const f32x4*>(Ad + 4);
            float fdv[8] = {d0[0], d0[1], d0[2], d0[3], d1[0], d1[1], d1[2], d1[3]};
            const int ob = (rr * 64 + lane) * 68 + j0;
            #pragma unroll
            for (int i = 0; i < 8; ++i)  s_o[ob + i]     = fsa0 * fdv[i];
            #pragma unroll
            for (int i = 0; i < 8; ++i)  s_o[ob + 8 + i] = fsa1 * fdv[i];
        }

        // CSR slot + n-write (one thread per edge)
        if (w == 0 && valid) {
            int pp = atomicAdd(&cursor[dst], 1);
            s_pos[rr * 64 + lane] = pp;
            float* np = ef + (size_t)pp * 52;
            np[48] = nx; np[49] = ny; np[50] = nz;
        }
    }
    __syncthreads();

    // ---- hc chunks (registers) for both rounds ----
    float hcr[2][16];
    #pragma unroll
    for (int rr = 0; rr < 2; ++rr) {
        const int hb = (rr * 64 + lane) * 65;
        #pragma unroll
        for (int i = 0; i < 16; ++i) hcr[rr][i] = fb2[j0 + i];
        #pragma unroll 4
        for (int j = 0; j < 64; ++j) {
            const float v = s_un[hb + j];
            const float* w2r = fw2 + j * 64 + j0;   // wave-uniform -> scalar
            #pragma unroll
            for (int i = 0; i < 16; ++i) hcr[rr][i] = fmaf(v, w2r[i], hcr[rr][i]);
        }
        #pragma unroll
        for (int i = 0; i < 16; ++i) hcr[rr][i] = silu_f(hcr[rr][i]);
    }
    __syncthreads();   // all h1 reads done -> rewrite region at stride 68

    #pragma unroll
    for (int rr = 0; rr < 2; ++rr) {
        const int hb = (rr * 64 + lane) * 68 + j0;
        #pragma unroll
        for (int i = 0; i < 16; ++i) s_un[hb + i] = hcr[rr][i];
    }
    __syncthreads();

    LOADB(Bb, 64);   // bias chunk in flight across fragment extraction

    // ---- extract per-lane A (h) and O (bias) fragments ----
    const int g = lane >> 4;                 // k-group
    const int mrow = w * 32 + (lane & 15);   // M-tile 0 row
    s16x8 AhF[2][2], AlF[2][2], OhF[2][2], OlF[2][2];
    #pragma unroll
    for (int mt = 0; mt < 2; ++mt) {
        const float* hr = s_un + (mrow + mt * 16) * 68;
        const float* orw = s_o + (mrow + mt * 16) * 68;
        f32x4 a0 = *reinterpret_cast<const f32x4*>(hr + g * 8);
        f32x4 a1 = *reinterpret_cast<const f32x4*>(hr + g * 8 + 4);
        split8(a0, a1, AhF[mt][0], AlF[mt][0]);
        f32x4 a2 = *reinterpret_cast<const f32x4*>(hr + 32 + g * 8);
        f32x4 a3 = *reinterpret_cast<const f32x4*>(hr + 32 + g * 8 + 4);
        split8(a2, a3, AhF[mt][1], AlF[mt][1]);
        f32x4 o0 = *reinterpret_cast<const f32x4*>(orw + g * 8);
        f32x4 o1 = *reinterpret_cast<const f32x4*>(orw + g * 8 + 4);
        split8(o0, o1, OhF[mt][0], OlF[mt][0]);
        f32x4 o2 = *reinterpret_cast<const f32x4*>(orw + 32 + g * 8);
        f32x4 o3 = *reinterpret_cast<const f32x4*>(orw + 32 + g * 8 + 4);
        split8(o2, o3, OhF[mt][1], OlF[mt][1]);
    }

    const int rb = w * 32 + (lane >> 4) * 4;   // first output row of this lane's D

    f32x4 acc[2][3];
    #pragma unroll
    for (int mt = 0; mt < 2; ++mt)
        #pragma unroll
        for (int t = 0; t < 3; ++t) acc[mt][t] = (f32x4){0.f, 0.f, 0.f, 0.f};

    // ---- bias tail FIRST (frees O-fragments before the main loop) ----
    __builtin_amdgcn_s_setprio(1);
    #pragma unroll
    for (int t = 0; t < 3; ++t) {
        #pragma unroll
        for (int sl = 0; sl < 2; ++sl) {
            s16x8 Bh = Bb[(sl * 3 + t) * 2];
            s16x8 Bl = Bb[(sl * 3 + t) * 2 + 1];
            acc[0][t] = __builtin_amdgcn_mfma_f32_16x16x32_bf16(OhF[0][sl], Bh, acc[0][t], 0, 0, 0);
            acc[0][t] = __builtin_amdgcn_mfma_f32_16x16x32_bf16(OhF[0][sl], Bl, acc[0][t], 0, 0, 0);
            acc[0][t] = __builtin_amdgcn_mfma_f32_16x16x32_bf16(OlF[0][sl], Bh, acc[0][t], 0, 0, 0);
            acc[1][t] = __builtin_amdgcn_mfma_f32_16x16x32_bf16(OhF[1][sl], Bh, acc[1][t], 0, 0, 0);
            acc[1][t] = __builtin_amdgcn_mfma_f32_16x16x32_bf16(OhF[1][sl], Bl, acc[1][t], 0, 0, 0);
            acc[1][t] = __builtin_amdgcn_mfma_f32_16x16x32_bf16(OlF[1][sl], Bh, acc[1][t], 0, 0, 0);
        }
    }
    __builtin_amdgcn_s_setprio(0);

    // ---- main K-loop: barrier-free, register double buffer, unroll x2 ----
    // Per u: ONE 36-MFMA cluster into six STATIC D accumulators, one result
    // wait, then all 24 o-scale fmafs.
#define MSTEP(BC, U) { \
    float ov[8]; \
    _Pragma("unroll") \
    for (int i = 0; i < 4; ++i) { \
        ov[i]     = s_o[(rb + i) * 68 + (U)]; \
        ov[4 + i] = s_o[(rb + 16 + i) * 68 + (U)]; \
    } \
    f32x4 D0 = {0.f, 0.f, 0.f, 0.f}, D1 = {0.f, 0.f, 0.f, 0.f}; \
    f32x4 D2 = {0.f, 0.f, 0.f, 0.f}, D3 = {0.f, 0.f, 0.f, 0.f}; \
    f32x4 D4 = {0.f, 0.f, 0.f, 0.f}, D5 = {0.f, 0.f, 0.f, 0.f}; \
    __builtin_amdgcn_s_setprio(1); \
    _Pragma("unroll") \
    for (int sl = 0; sl < 2; ++sl) { \
        s16x8 Bh0 = BC[(sl * 3 + 0) * 2], Bl0 = BC[(sl * 3 + 0) * 2 + 1]; \
        s16x8 Bh1 = BC[(sl * 3 + 1) * 2], Bl1 = BC[(sl * 3 + 1) * 2 + 1]; \
        s16x8 Bh2 = BC[(sl * 3 + 2) * 2], Bl2 = BC[(sl * 3 + 2) * 2 + 1]; \
        D0 = __builtin_amdgcn_mfma_f32_16x16x32_bf16(AhF[0][sl], Bh0, D0, 0, 0, 0); \
        D1 = __builtin_amdgcn_mfma_f32_16x16x32_bf16(AhF[1][sl], Bh0, D1, 0, 0, 0); \
        D2 = __builtin_amdgcn_mfma_f32_16x16x32_bf16(AhF[0][sl], Bh1, D2, 0, 0, 0); \
        D3 = __builtin_amdgcn_mfma_f32_16x16x32_bf16(AhF[1][sl], Bh1, D3, 0, 0, 0); \
        D4 = __builtin_amdgcn_mfma_f32_16x16x32_bf16(AhF[0][sl], Bh2, D4, 0, 0, 0); \
        D5 = __builtin_amdgcn_mfma_f32_16x16x32_bf16(AhF[1][sl], Bh2, D5, 0, 0, 0); \
        D0 = __builtin_amdgcn_mfma_f32_16x16x32_bf16(AlF[0][sl], Bh0, D0, 0, 0, 0); \
        D1 = __builtin_amdgcn_mfma_f32_16x16x32_bf16(AlF[1][sl], Bh0, D1, 0, 0, 0); \
        D2 = __builtin_amdgcn_mfma_f32_16x16x32_bf16(AlF[0][sl], Bh1, D2, 0, 0, 0); \
        D3 = __builtin_amdgcn_mfma_f32_16x16x32_bf16(AlF[1][sl], Bh1, D3, 0, 0, 0); \
        D4 = __builtin_amdgcn_mfma_f32_16x16x32_bf16(AlF[0][sl], Bh2, D4, 0, 0, 0); \
        D5 = __builtin_amdgcn_mfma_f32_16x16x32_bf16(AlF[1][sl], Bh2, D5, 0, 0, 0); \
        D0 = __builtin_amdgcn_mfma_f32_16x16x32_bf16(AhF[0][sl], Bl0, D0, 0, 0, 0); \
        D1 = __builtin_amdgcn_mfma_f32_16x16x32_bf16(AhF[1][sl], Bl0, D1, 0, 0, 0); \
        D2 = __builtin_amdgcn_mfma_f32_16x16x32_bf16(AhF[0][sl], Bl1, D2, 0, 0, 0); \
        D3 = __builtin_amdgcn_mfma_f32_16x16x32_bf16(AhF[1][sl], Bl1, D3, 0, 0, 0); \
        D4 = __builtin_amdgcn_mfma_f32_16x16x32_bf16(AhF[0][sl], Bl2, D4, 0, 0, 0); \
        D5 = __builtin_amdgcn_mfma_f32_16x16x32_bf16(AhF[1][sl], Bl2, D5, 0, 0, 0); \
    } \
    __builtin_amdgcn_s_setprio(0); \
    _Pragma("unroll") \
    for (int i = 0; i < 4; ++i) { \
        acc[0][0][i] = fmaf(ov[i],     D0[i], acc[0][0][i]); \
        acc[1][0][i] = fmaf(ov[4 + i], D1[i], acc[1][0][i]); \
        acc[0][1][i] = fmaf(ov[i],     D2[i], acc[0][1][i]); \
        acc[1][1][i] = fmaf(ov[4 + i], D3[i], acc[1][1][i]); \
        acc[0][2][i] = fmaf(ov[i],     D4[i], acc[0][2][i]); \
        acc[1][2][i] = fmaf(ov[4 + i], D5[i], acc[1][2][i]); \
    } }

    for (int u = 0; u < 64; u += 2) {
        LOADB(Bb, u + 1);
        MSTEP(Ba, u);
        if (u + 2 < 64) LOADB(Ba, u + 2);
        MSTEP(Bb, u + 1);
    }
#undef MSTEP
#undef LOADB

    // ---- write m to CSR slot: row = rb + mt*16 + i, slot = s_pos[row] ----
    #pragma unroll
    for (int mt = 0; mt < 2; ++mt) {
        const int row = rb + mt * 16;
        #pragma unroll
        for (int t = 0; t < 3; ++t) {
            #pragma unroll
            for (int i = 0; i < 4; ++i) {
                if (e0 + row + i < E) {
                    const int pp = s_pos[row + i];
                    ef[(size_t)pp * 52 + t * 16 + (lane & 15)] = acc[mt][t][i];
                }
            }
        }
    }
}

// ---------------- kernel 4: gather-reduce per node (STREAMING: ef is CSR-ordered) ----------------
__global__ __launch_bounds__(256) void k_gather(const float* __restrict__ ef,
                                                const int* __restrict__ offs,
                                                float* __restrict__ out, int N) {
    const int lane = threadIdx.x & 63;
    const int node = blockIdx.x * 4 + (threadIdx.x >> 6);
    if (node >= N) return;

    const int beg = offs[node];
    const int end = offs[node + 1];

    int mi[4], ii[4], jj[4], mode[4];
    #pragma unroll
    for (int t = 0; t < 4; ++t) {
        int c = lane + 64 * t;
        if (c < 16)       { mi[t] = c;                 ii[t] = 0;     jj[t] = 0;     mode[t] = 0; }
        else if (c < 64)  { int u = c - 16; mi[t] = 16 + u / 3; ii[t] = u % 3; jj[t] = 0; mode[t] = 1; }
        else if (c < 208) { int u = c - 64; mi[t] = 32 + u / 9; int rr = u % 9; ii[t] = rr / 3; jj[t] = rr % 3; mode[t] = 2; }
        else              { mi[t] = 0; ii[t] = 0; jj[t] = 0; mode[t] = 3; }
    }

    float acc[4] = {0.f, 0.f, 0.f, 0.f};
    #pragma unroll 4
    for (int k = beg; k < end; ++k) {
        const float* b = ef + (size_t)k * 52;   // contiguous stream per node
        float v = (lane < 51) ? b[lane] : 0.0f;
        float n0 = __shfl(v, 48);
        float n1 = __shfl(v, 49);
        float n2 = __shfl(v, 50);
        #pragma unroll
        for (int t = 0; t < 4; ++t) {
            float mval = __shfl(v, mi[t]);
            float ni = (ii[t] == 0) ? n0 : ((ii[t] == 1) ? n1 : n2);
            float nj = (jj[t] == 0) ? n0 : ((jj[t] == 1) ? n1 : n2);
            float f  = (mode[t] == 0) ? 1.0f
                     : (mode[t] == 1) ? ni
                     : (mode[t] == 2) ? ni * nj
                     : 0.0f;
            acc[t] = fmaf(mval, f, acc[t]);
        }
    }

    const float inv = 1.0f / fmaxf((float)(end - beg), 1.0f);
    float* op = out + (size_t)node * 208;
    op[lane]        = acc[0] * inv;
    op[lane + 64]   = acc[1] * inv;
    op[lane + 128]  = acc[2] * inv;
    if (lane < 16) op[lane + 192] = acc[3] * inv;
}

extern "C" void kernel_launch(void* const* d_in, const int* in_sizes, int n_in,
                              void* d_out, int out_size, void* d_ws, size_t ws_size,
                              hipStream_t stream) {
    const float* pos    = (const float*)d_in[0];
    const int*   A      = (const int*)d_in[1];
    const int*   batch  = (const int*)d_in[2];
    const int*   esrc   = (const int*)d_in[3];
    const int*   edst   = (const int*)d_in[4];
    const float* eshift = (const float*)d_in[5];
    const float* cell   = (const float*)d_in[6];
    const float* embt   = (const float*)d_in[7];
    const float* mw1    = (const float*)d_in[8];
    const float* mb1    = (const float*)d_in[9];
    const float* mw2    = (const float*)d_in[10];
    const float* mb2    = (const float*)d_in[11];
    const float* fw1    = (const float*)d_in[12];
    const float* fb1    = (const float*)d_in[13];
    const float* fw2    = (const float*)d_in[14];
    const float* fb2    = (const float*)d_in[15];
    const float* w3     = (const float*)d_in[16];
    const float* b3     = (const float*)d_in[17];
    float* out = (float*)d_out;

    const int N = in_sizes[1];
    const int E = in_sizes[3];

    char* p = (char*)d_ws;
    auto take = [&](size_t bytes) {
        char* q = p;
        p += (bytes + 255) & ~(size_t)255;
        return q;
    };
    ushort* wz    = (ushort*)take((size_t)130 * 3 * 2 * 512 * sizeof(ushort)); // ~780 KiB
    float* Ai     = (float*)take((size_t)N * 8 * sizeof(float));
    int*   deg    = (int*)  take((size_t)N * sizeof(int));
    int*   offs   = (int*)  take((size_t)(N + 1) * sizeof(int));
    int*   cursor = (int*)  take((size_t)N * sizeof(int));
    float* ef     = (float*)take((size_t)E * 52 * sizeof(float)); // ~20.8 MiB

    hipMemsetAsync(deg, 0, (size_t)N * sizeof(int), stream);

    const int aiB = (N + 255) / 256;
    const int histB = (E + 255) / 256;
    k_setup<<<780 + aiB + histB, 256, 0, stream>>>(w3, b3, wz, A, embt, mw1, mb1,
                                                   mw2, mb2, Ai, edst, deg, N, E, aiB);
    k_scan<<<1, 1024, 0, stream>>>(deg, offs, cursor, N);
    k_edge<<<(E + 127) / 128, 256, 0, stream>>>(pos, batch, esrc, edst, eshift, cell,
                                                fw1, fb1, fw2, fb2, wz, Ai,
                                                ef, cursor, E);
    k_gather<<<(N + 3) / 4, 256, 0, stream>>>(ef, offs, out, N);
}

// Round 14
// 235.833 us; speedup vs baseline: 1.1536x; 1.0073x over previous
//
#include <hip/hip_runtime.h>
#include <math.h>
#include <stdint.h>

// Shapes (fixed by the reference)
// N=10000, E=100000, G=64, NB=16, EMB=16, S=8, COUT=16, LMAX=2
// WNUM = 3*16*8*8 = 3072 ; ef width = 16 + 48 + 144 = 208
// Per-edge compact result: m[48] (l*16+o) + n[3], stored as 52 floats,
// written in CSR ORDER (slot = pos[e]) so k_gather reads are streaming.
//
// Main contraction as a fused GEMM via MFMA:
//   m[e][lo] = sum_ab o[e][ab] * ( sum_c h[e][c] * w3[c][lo*64+ab] ) + bias
// Per K-chunk u (= one ab), MFMA computes D = (h . B_ab) with h split into
// bf16 hi+lo (3 products, fp32 accum); then acc += o[e][ab] * D in exact f32.
// B-fragments stream global->reg (depth-2 double buffer; depth-3 spills, r9;
// LDS-shared variants are slower, r6/r11). o is stored TRANSPOSED in LDS
// (s_oT[ab][edge]) so the per-u read is 2 broadcast ds_read_b128 instead of
// 8 scattered ds_read_b32.

typedef float  f32x4  __attribute__((ext_vector_type(4)));
typedef short  s16x8  __attribute__((ext_vector_type(8)));
typedef __bf16 bf16x8 __attribute__((ext_vector_type(8)));

__device__ __forceinline__ float silu_f(float x) {
    return x / (1.0f + __expf(-x));
}

// split 8 f32 (two f32x4, k-local order j=0..7) into bf16 hi + lo fragments
__device__ __forceinline__ void split8(f32x4 a, f32x4 b, s16x8& hi, s16x8& lo) {
    bf16x8 h8, l8;
    #pragma unroll
    for (int i = 0; i < 4; ++i) {
        float z = a[i]; __bf16 zh = (__bf16)z; h8[i] = zh; l8[i] = (__bf16)(z - (float)zh);
        float y = b[i]; __bf16 yh = (__bf16)y; h8[4 + i] = yh; l8[4 + i] = (__bf16)(y - (float)yh);
    }
    hi = __builtin_bit_cast(s16x8, h8);
    lo = __builtin_bit_cast(s16x8, l8);
}

// ---------------- kernel 1 (fused setup): prep wz | node Ai | edge_dst hist ----------------
// wz layout (verified r5-r13): wz[((s*3+tt)*2+plane)*512 + l*8 + j], where
// s<128: ab=s>>1, c=(s&1)*32+kl ; s>=128: ab=(s-128)*32+kl ; kl=(l>>4)*8+j ;
// lo = tt*16 + (l&15).
// Prep enumerates w3 LINEARLY (coalesced reads), scatters wz via inverse map:
//   s=(ab<<1)|(c>>5), kl=c&31, j=kl&7, l=((kl>>3)<<4)|(lo&15), tt=lo>>4.
__global__ __launch_bounds__(256) void k_setup(const float* __restrict__ w3,
                                               const float* __restrict__ b3,
                                               ushort* __restrict__ wz,
                                               const int* __restrict__ A,
                                               const float* __restrict__ embt,
                                               const float* __restrict__ w1,
                                               const float* __restrict__ b1,
                                               const float* __restrict__ w2,
                                               const float* __restrict__ b2,
                                               float* __restrict__ Ai,
                                               const int* __restrict__ edst,
                                               int* __restrict__ deg,
                                               int N, int E, int aiB) {
    const int b = blockIdx.x;
    const int tid = threadIdx.x;
    if (b < 768) {                         // ---- w3 prep: 768*256 = 196608 = 64*48*64
        const int idx = b * 256 + tid;     // idx = c*3072 + lo*64 + ab (linear in w3)
        const int c   = idx / 3072;
        const int rem = idx - c * 3072;
        const int lo  = rem >> 6;
        const int ab  = rem & 63;
        const float v = w3[idx];           // coalesced
        const int s  = (ab << 1) | (c >> 5);
        const int kl = c & 31;
        const int j  = kl & 7;
        const int l  = ((kl >> 3) << 4) | (lo & 15);
        const int tt = lo >> 4;
        __bf16 hi  = (__bf16)v;
        __bf16 lor = (__bf16)(v - (float)hi);
        const size_t base = (size_t)(s * 3 + tt) * 2 * 512 + l * 8 + j;
        wz[base]       = __builtin_bit_cast(ushort, hi);
        wz[base + 512] = __builtin_bit_cast(ushort, lor);
    } else if (b < 780) {                  // ---- bias prep: 12*256 = 3072 = 48*64
        const int i2 = (b - 768) * 256 + tid;   // i2 = lo*64 + ab (linear in b3)
        const int lo = i2 >> 6;
        const int ab = i2 & 63;
        const float v = b3[i2];            // coalesced
        const int s  = 128 + (ab >> 5);
        const int kl = ab & 31;
        const int j  = kl & 7;
        const int l  = ((kl >> 3) << 4) | (lo & 15);
        const int tt = lo >> 4;
        __bf16 hi  = (__bf16)v;
        __bf16 lor = (__bf16)(v - (float)hi);
        const size_t base = (size_t)(s * 3 + tt) * 2 * 512 + l * 8 + j;
        wz[base]       = __builtin_bit_cast(ushort, hi);
        wz[base + 512] = __builtin_bit_cast(ushort, lor);
    } else if (b < 780 + aiB) {            // ---- node Ai
        int i = (b - 780) * 256 + tid;
        if (i >= N) return;
        float e[16];
        const float* er = embt + A[i] * 16;
        #pragma unroll
        for (int k = 0; k < 16; ++k) e[k] = er[k];
        float h1[64];
        #pragma unroll
        for (int j = 0; j < 64; ++j) {
            float a = b1[j];
            #pragma unroll
            for (int k = 0; k < 16; ++k) a = fmaf(e[k], w1[k * 64 + j], a);
            h1[j] = silu_f(a);
        }
        #pragma unroll
        for (int o = 0; o < 8; ++o) {
            float a = b2[o];
            #pragma unroll
            for (int j = 0; j < 64; ++j) a = fmaf(h1[j], w2[j * 8 + o], a);
            Ai[i * 8 + o] = a;
        }
    } else {                               // ---- histogram of edge_dst
        int e = (b - 780 - aiB) * 256 + tid;
        if (e < E) atomicAdd(&deg[edst[e]], 1);
    }
}

// ---------------- kernel 2: single-block exclusive scan (N=10000), 1024 threads ----------------
__global__ __launch_bounds__(1024) void k_scan(const int* __restrict__ deg,
                                               int* __restrict__ offs,
                                               int* __restrict__ cursor, int N) {
    __shared__ int part[1024];
    const int t = threadIdx.x;
    const int chunk = (N + 1023) / 1024;
    const int beg = t * chunk;
    const int end = min(beg + chunk, N);
    int s = 0;
    for (int i = beg; i < end; ++i) s += deg[i];
    part[t] = s;
    __syncthreads();
    for (int off = 1; off < 1024; off <<= 1) {
        int v = (t >= off) ? part[t - off] : 0;
        __syncthreads();
        part[t] += v;
        __syncthreads();
    }
    int run = (t == 0) ? 0 : part[t - 1];
    for (int i = beg; i < end; ++i) {
        offs[i] = run;
        cursor[i] = run;
        run += deg[i];
    }
    if (t == 1023) offs[N] = part[1023];
}

// ---------------- kernel 3: per-edge compute via MFMA ----------------
// Block = 256 threads = 4 waves = 128 edges (M=32 per wave: 2 x 16-row tiles).
// Front end (verified) runs twice (rows 0-63, 64-127); h moves to per-lane
// bf16 hi/lo fragments (registers). Main K-loop: BARRIER-FREE -- B fragments
// in a depth-2 register double buffer, L1/L2-shared across waves.
// o stored transposed: s_oT[ab][edge] (stride 132) -> per-u ov read is
// 2 broadcast ds_read_b128. ef writes go to CSR slot s_pos[row].
__global__ __launch_bounds__(256, 2) void k_edge(
    const float* __restrict__ pos, const int* __restrict__ batch,
    const int* __restrict__ esrc, const int* __restrict__ edst,
    const float* __restrict__ eshift, const float* __restrict__ cell,
    const float* __restrict__ fw1, const float* __restrict__ fb1,
    const float* __restrict__ fw2, const float* __restrict__ fb2,
    const ushort* __restrict__ wz,
    const float* __restrict__ Ai, float* __restrict__ ef,
    int* __restrict__ cursor, int E) {

    __shared__ __align__(16) float s_un[8704];       // h1 (stride 65) -> h (stride 68)
    __shared__ __align__(16) float s_oT[64 * 132];   // o[ab][edge], stride 132
    __shared__ int s_pos[128];                       // CSR slot per block-local edge

    const int tid  = threadIdx.x;
    const int lane = tid & 63;
    const int w    = __builtin_amdgcn_readfirstlane(tid >> 6);   // wave id
    const int e0   = blockIdx.x * 128;
    const int j0   = w * 16;                                     // c-chunk

    const f32x4* wzv = reinterpret_cast<const f32x4*>(wz);

    // B-fragment load: 12 x 16B per lane, chunk U (perfectly coalesced, L1-shared)
    s16x8 Ba[12], Bb[12];
#define LOADB(ARR, U) { \
    const f32x4* gs = wzv + (size_t)(U) * 768 + lane; \
    _Pragma("unroll") \
    for (int f = 0; f < 12; ++f) ARR[f] = __builtin_bit_cast(s16x8, gs[f * 64]); }

    LOADB(Ba, 0);   // prologue: chunk 0 in flight across the whole front end

    // ---- front end, two rounds of 64 edges ----
    #pragma unroll
    for (int rr = 0; rr < 2; ++rr) {
        const int e = e0 + rr * 64 + lane;
        const bool valid = (e < E);
        const int ec = valid ? e : (E - 1);
        const int src = esrc[ec];
        const int dst = edst[ec];

        const int g0 = batch[src];
        const float s0 = eshift[ec * 3 + 0], s1 = eshift[ec * 3 + 1], s2 = eshift[ec * 3 + 2];
        const float* cl = cell + g0 * 9;
        float vx = pos[dst * 3 + 0] - pos[src * 3 + 0] + s0 * cl[0] + s1 * cl[3] + s2 * cl[6];
        float vy = pos[dst * 3 + 1] - pos[src * 3 + 1] + s0 * cl[1] + s1 * cl[4] + s2 * cl[7];
        float vz = pos[dst * 3 + 2] - pos[src * 3 + 2] + s0 * cl[2] + s1 * cl[5] + s2 * cl[8];
        float r = sqrtf(vx * vx + vy * vy + vz * vz);
        float rinv = 1.0f / fmaxf(r, 1e-9f);
        float nx = vx * rinv, ny = vy * rinv, nz = vz * rinv;

        float embv[16];
        const float step = 4.0f / 17.0f;
        const float sc = 4.0f / 1.12f;
        #pragma unroll
        for (int k = 0; k < 16; ++k) {
            float d = (r - (float)(k + 1) * step) / step;
            embv[k] = __expf(-d * d) * sc;
        }

        // h1 chunk -> s_un (stride 65)
        const int hb = (rr * 64 + lane) * 65;
        #pragma unroll
        for (int jj = 0; jj < 16; ++jj) {
            const int j = j0 + jj;
            float a = fb1[j];
            #pragma unroll
            for (int k = 0; k < 16; ++k) a = fmaf(embv[k], fw1[k * 64 + j], a);
            s_un[hb + j] = silu_f(a);
        }

        // o chunk -> s_oT (transposed: [ab][edge], stride 132; lane varies -> conflict-free)
        {
            const float* As = Ai + (size_t)src * 8;
            const float* Ad = Ai + (size_t)dst * 8;
            float fsa0 = As[2 * w], fsa1 = As[2 * w + 1];
            f32x4 d0 = *reinterpret_cast<const f32x4*>(Ad);
            f32x4 d1 = *reinterpret_cast<const f32x4*>(Ad + 4);
            float fdv[8] = {d0[0], d0[1], d0[2], d0[3], d1[0], d1[1], d1[2], d1[3]};
            const int erow = rr * 64 + lane;
            #pragma unroll
            for (int i = 0; i < 8; ++i)  s_oT[(j0 + i) * 132 + erow]     = fsa0 * fdv[i];
            #pragma unroll
            for (int i = 0; i < 8; ++i)  s_oT[(j0 + 8 + i) * 132 + erow] = fsa1 * fdv[i];
        }

        // CSR slot + n-write (one thread per edge)
        if (w == 0 && valid) {
            int pp = atomicAdd(&cursor[dst], 1);
            s_pos[rr * 64 + lane] = pp;
            float* np = ef + (size_t)pp * 52;
            np[48] = nx; np[49] = ny; np[50] = nz;
        }
    }
    __syncthreads();

    // ---- hc chunks (registers) for both rounds ----
    float hcr[2][16];
    #pragma unroll
    for (int rr = 0; rr < 2; ++rr) {
        const int hb = (rr * 64 + lane) * 65;
        #pragma unroll
        for (int i = 0; i < 16; ++i) hcr[rr][i] = fb2[j0 + i];
        #pragma unroll 4
        for (int j = 0; j < 64; ++j) {
            const float v = s_un[hb + j];
            const float* w2r = fw2 + j * 64 + j0;   // wave-uniform -> scalar
            #pragma unroll
            for (int i = 0; i < 16; ++i) hcr[rr][i] = fmaf(v, w2r[i], hcr[rr][i]);
        }
        #pragma unroll
        for (int i = 0; i < 16; ++i) hcr[rr][i] = silu_f(hcr[rr][i]);
    }
    __syncthreads();   // all h1 reads done -> rewrite region at stride 68

    #pragma unroll
    for (int rr = 0; rr < 2; ++rr) {
        const int hb = (rr * 64 + lane) * 68 + j0;
        #pragma unroll
        for (int i = 0; i < 16; ++i) s_un[hb + i] = hcr[rr][i];
    }
    __syncthreads();

    LOADB(Bb, 64);   // bias chunk in flight across fragment extraction

    // ---- extract per-lane A (h) and O (bias) fragments ----
    const int g = lane >> 4;                 // k-group
    const int mrow = w * 32 + (lane & 15);   // M-tile 0 row
    s16x8 AhF[2][2], AlF[2][2], OhF[2][2], OlF[2][2];
    #pragma unroll
    for (int mt = 0; mt < 2; ++mt) {
        const float* hr = s_un + (mrow + mt * 16) * 68;
        f32x4 a0 = *reinterpret_cast<const f32x4*>(hr + g * 8);
        f32x4 a1 = *reinterpret_cast<const f32x4*>(hr + g * 8 + 4);
        split8(a0, a1, AhF[mt][0], AlF[mt][0]);
        f32x4 a2 = *reinterpret_cast<const f32x4*>(hr + 32 + g * 8);
        f32x4 a3 = *reinterpret_cast<const f32x4*>(hr + 32 + g * 8 + 4);
        split8(a2, a3, AhF[mt][1], AlF[mt][1]);
        // O from transposed layout: o[row][ab] = s_oT[ab*132 + row]
        const int row = mrow + mt * 16;
        f32x4 o0, o1, o2, o3;
        #pragma unroll
        for (int k = 0; k < 4; ++k) {
            o0[k] = s_oT[(g * 8 + k) * 132 + row];
            o1[k] = s_oT[(g * 8 + 4 + k) * 132 + row];
            o2[k] = s_oT[(32 + g * 8 + k) * 132 + row];
            o3[k] = s_oT[(32 + g * 8 + 4 + k) * 132 + row];
        }
        split8(o0, o1, OhF[mt][0], OlF[mt][0]);
        split8(o2, o3, OhF[mt][1], OlF[mt][1]);
    }

    const int rb = w * 32 + (lane >> 4) * 4;   // first output row of this lane's D

    f32x4 acc[2][3];
    #pragma unroll
    for (int mt = 0; mt < 2; ++mt)
        #pragma unroll
        for (int t = 0; t < 3; ++t) acc[mt][t] = (f32x4){0.f, 0.f, 0.f, 0.f};

    // ---- bias tail FIRST (frees O-fragments before the main loop) ----
    __builtin_amdgcn_s_setprio(1);
    #pragma unroll
    for (int t = 0; t < 3; ++t) {
        #pragma unroll
        for (int sl = 0; sl < 2; ++sl) {
            s16x8 Bh = Bb[(sl * 3 + t) * 2];
            s16x8 Bl = Bb[(sl * 3 + t) * 2 + 1];
            acc[0][t] = __builtin_amdgcn_mfma_f32_16x16x32_bf16(OhF[0][sl], Bh, acc[0][t], 0, 0, 0);
            acc[0][t] = __builtin_amdgcn_mfma_f32_16x16x32_bf16(OhF[0][sl], Bl, acc[0][t], 0, 0, 0);
            acc[0][t] = __builtin_amdgcn_mfma_f32_16x16x32_bf16(OlF[0][sl], Bh, acc[0][t], 0, 0, 0);
            acc[1][t] = __builtin_amdgcn_mfma_f32_16x16x32_bf16(OhF[1][sl], Bh, acc[1][t], 0, 0, 0);
            acc[1][t] = __builtin_amdgcn_mfma_f32_16x16x32_bf16(OhF[1][sl], Bl, acc[1][t], 0, 0, 0);
            acc[1][t] = __builtin_amdgcn_mfma_f32_16x16x32_bf16(OlF[1][sl], Bh, acc[1][t], 0, 0, 0);
        }
    }
    __builtin_amdgcn_s_setprio(0);

    // ---- main K-loop: barrier-free, register double buffer, unroll x2 ----
    // Per u: 2 broadcast ds_read_b128 (ov), ONE 36-MFMA cluster into six
    // STATIC D accumulators, one result wait, then all 24 o-scale fmafs.
#define MSTEP(BC, U) { \
    f32x4 ovA = *reinterpret_cast<const f32x4*>(&s_oT[(U) * 132 + rb]); \
    f32x4 ovB = *reinterpret_cast<const f32x4*>(&s_oT[(U) * 132 + rb + 16]); \
    f32x4 D0 = {0.f, 0.f, 0.f, 0.f}, D1 = {0.f, 0.f, 0.f, 0.f}; \
    f32x4 D2 = {0.f, 0.f, 0.f, 0.f}, D3 = {0.f, 0.f, 0.f, 0.f}; \
    f32x4 D4 = {0.f, 0.f, 0.f, 0.f}, D5 = {0.f, 0.f, 0.f, 0.f}; \
    __builtin_amdgcn_s_setprio(1); \
    _Pragma("unroll") \
    for (int sl = 0; sl < 2; ++sl) { \
        s16x8 Bh0 = BC[(sl * 3 + 0) * 2], Bl0 = BC[(sl * 3 + 0) * 2 + 1]; \
        s16x8 Bh1 = BC[(sl * 3 + 1) * 2], Bl1 = BC[(sl * 3 + 1) * 2 + 1]; \
        s16x8 Bh2 = BC[(sl * 3 + 2) * 2], Bl2 = BC[(sl * 3 + 2) * 2 + 1]; \
        D0 = __builtin_amdgcn_mfma_f32_16x16x32_bf16(AhF[0][sl], Bh0, D0, 0, 0, 0); \
        D1 = __builtin_amdgcn_mfma_f32_16x16x32_bf16(AhF[1][sl], Bh0, D1, 0, 0, 0); \
        D2 = __builtin_amdgcn_mfma_f32_16x16x32_bf16(AhF[0][sl], Bh1, D2, 0, 0, 0); \
        D3 = __builtin_amdgcn_mfma_f32_16x16x32_bf16(AhF[1][sl], Bh1, D3, 0, 0, 0); \
        D4 = __builtin_amdgcn_mfma_f32_16x16x32_bf16(AhF[0][sl], Bh2, D4, 0, 0, 0); \
        D5 = __builtin_amdgcn_mfma_f32_16x16x32_bf16(AhF[1][sl], Bh2, D5, 0, 0, 0); \
        D0 = __builtin_amdgcn_mfma_f32_16x16x32_bf16(AlF[0][sl], Bh0, D0, 0, 0, 0); \
        D1 = __builtin_amdgcn_mfma_f32_16x16x32_bf16(AlF[1][sl], Bh0, D1, 0, 0, 0); \
        D2 = __builtin_amdgcn_mfma_f32_16x16x32_bf16(AlF[0][sl], Bh1, D2, 0, 0, 0); \
        D3 = __builtin_amdgcn_mfma_f32_16x16x32_bf16(AlF[1][sl], Bh1, D3, 0, 0, 0); \
        D4 = __builtin_amdgcn_mfma_f32_16x16x32_bf16(AlF[0][sl], Bh2, D4, 0, 0, 0); \
        D5 = __builtin_amdgcn_mfma_f32_16x16x32_bf16(AlF[1][sl], Bh2, D5, 0, 0, 0); \
        D0 = __builtin_amdgcn_mfma_f32_16x16x32_bf16(AhF[0][sl], Bl0, D0, 0, 0, 0); \
        D1 = __builtin_amdgcn_mfma_f32_16x16x32_bf16(AhF[1][sl], Bl0, D1, 0, 0, 0); \
        D2 = __builtin_amdgcn_mfma_f32_16x16x32_bf16(AhF[0][sl], Bl1, D2, 0, 0, 0); \
        D3 = __builtin_amdgcn_mfma_f32_16x16x32_bf16(AhF[1][sl], Bl1, D3, 0, 0, 0); \
        D4 = __builtin_amdgcn_mfma_f32_16x16x32_bf16(AhF[0][sl], Bl2, D4, 0, 0, 0); \
        D5 = __builtin_amdgcn_mfma_f32_16x16x32_bf16(AhF[1][sl], Bl2, D5, 0, 0, 0); \
    } \
    __builtin_amdgcn_s_setprio(0); \
    _Pragma("unroll") \
    for (int i = 0; i < 4; ++i) { \
        acc[0][0][i] = fmaf(ovA[i], D0[i], acc[0][0][i]); \
        acc[1][0][i] = fmaf(ovB[i], D1[i], acc[1][0][i]); \
        acc[0][1][i] = fmaf(ovA[i], D2[i], acc[0][1][i]); \
        acc[1][1][i] = fmaf(ovB[i], D3[i], acc[1][1][i]); \
        acc[0][2][i] = fmaf(ovA[i], D4[i], acc[0][2][i]); \
        acc[1][2][i] = fmaf(ovB[i], D5[i], acc[1][2][i]); \
    } }

    for (int u = 0; u < 64; u += 2) {
        LOADB(Bb, u + 1);
        MSTEP(Ba, u);
        if (u + 2 < 64) LOADB(Ba, u + 2);
        MSTEP(Bb, u + 1);
    }
#undef MSTEP
#undef LOADB

    // ---- write m to CSR slot: row = rb + mt*16 + i, slot = s_pos[row] ----
    #pragma unroll
    for (int mt = 0; mt < 2; ++mt) {
        const int row = rb + mt * 16;
        #pragma unroll
        for (int t = 0; t < 3; ++t) {
            #pragma unroll
            for (int i = 0; i < 4; ++i) {
                if (e0 + row + i < E) {
                    const int pp = s_pos[row + i];
                    ef[(size_t)pp * 52 + t * 16 + (lane & 15)] = acc[mt][t][i];
                }
            }
        }
    }
}

// ---------------- kernel 4: gather-reduce per node (STREAMING: ef is CSR-ordered) ----------------
__global__ __launch_bounds__(256) void k_gather(const float* __restrict__ ef,
                                                const int* __restrict__ offs,
                                                float* __restrict__ out, int N) {
    const int lane = threadIdx.x & 63;
    const int node = blockIdx.x * 4 + (threadIdx.x >> 6);
    if (node >= N) return;

    const int beg = offs[node];
    const int end = offs[node + 1];

    int mi[4], ii[4], jj[4], mode[4];
    #pragma unroll
    for (int t = 0; t < 4; ++t) {
        int c = lane + 64 * t;
        if (c < 16)       { mi[t] = c;                 ii[t] = 0;     jj[t] = 0;     mode[t] = 0; }
        else if (c < 64)  { int u = c - 16; mi[t] = 16 + u / 3; ii[t] = u % 3; jj[t] = 0; mode[t] = 1; }
        else if (c < 208) { int u = c - 64; mi[t] = 32 + u / 9; int rr = u % 9; ii[t] = rr / 3; jj[t] = rr % 3; mode[t] = 2; }
        else              { mi[t] = 0; ii[t] = 0; jj[t] = 0; mode[t] = 3; }
    }

    float acc[4] = {0.f, 0.f, 0.f, 0.f};
    #pragma unroll 4
    for (int k = beg; k < end; ++k) {
        const float* b = ef + (size_t)k * 52;   // contiguous stream per node
        float v = (lane < 51) ? b[lane] : 0.0f;
        float n0 = __shfl(v, 48);
        float n1 = __shfl(v, 49);
        float n2 = __shfl(v, 50);
        #pragma unroll
        for (int t = 0; t < 4; ++t) {
            float mval = __shfl(v, mi[t]);
            float ni = (ii[t] == 0) ? n0 : ((ii[t] == 1) ? n1 : n2);
            float nj = (jj[t] == 0) ? n0 : ((jj[t] == 1) ? n1 : n2);
            float f  = (mode[t] == 0) ? 1.0f
                     : (mode[t] == 1) ? ni
                     : (mode[t] == 2) ? ni * nj
                     : 0.0f;
            acc[t] = fmaf(mval, f, acc[t]);
        }
    }

    const float inv = 1.0f / fmaxf((float)(end - beg), 1.0f);
    float* op = out + (size_t)node * 208;
    op[lane]        = acc[0] * inv;
    op[lane + 64]   = acc[1] * inv;
    op[lane + 128]  = acc[2] * inv;
    if (lane < 16) op[lane + 192] = acc[3] * inv;
}

extern "C" void kernel_launch(void* const* d_in, const int* in_sizes, int n_in,
                              void* d_out, int out_size, void* d_ws, size_t ws_size,
                              hipStream_t stream) {
    const float* pos    = (const float*)d_in[0];
    const int*   A      = (const int*)d_in[1];
    const int*   batch  = (const int*)d_in[2];
    const int*   esrc   = (const int*)d_in[3];
    const int*   edst   = (const int*)d_in[4];
    const float* eshift = (const float*)d_in[5];
    const float* cell   = (const float*)d_in[6];
    const float* embt   = (const float*)d_in[7];
    const float* mw1    = (const float*)d_in[8];
    const float* mb1    = (const float*)d_in[9];
    const float* mw2    = (const float*)d_in[10];
    const float* mb2    = (const float*)d_in[11];
    const float* fw1    = (const float*)d_in[12];
    const float* fb1    = (const float*)d_in[13];
    const float* fw2    = (const float*)d_in[14];
    const float* fb2    = (const float*)d_in[15];
    const float* w3     = (const float*)d_in[16];
    const float* b3     = (const float*)d_in[17];
    float* out = (float*)d_out;

    const int N = in_sizes[1];
    const int E = in_sizes[3];

    char* p = (char*)d_ws;
    auto take = [&](size_t bytes) {
        char* q = p;
        p += (bytes + 255) & ~(size_t)255;
        return q;
    };
    ushort* wz    = (ushort*)take((size_t)130 * 3 * 2 * 512 * sizeof(ushort)); // ~780 KiB
    float* Ai     = (float*)take((size_t)N * 8 * sizeof(float));
    int*   deg    = (int*)  take((size_t)N * sizeof(int));
    int*   offs   = (int*)  take((size_t)(N + 1) * sizeof(int));
    int*   cursor = (int*)  take((size_t)N * sizeof(int));
    float* ef     = (float*)take((size_t)E * 52 * sizeof(float)); // ~20.8 MiB

    hipMemsetAsync(deg, 0, (size_t)N * sizeof(int), stream);

    const int aiB = (N + 255) / 256;
    const int histB = (E + 255) / 256;
    k_setup<<<780 + aiB + histB, 256, 0, stream>>>(w3, b3, wz, A, embt, mw1, mb1,
                                                   mw2, mb2, Ai, edst, deg, N, E, aiB);
    k_scan<<<1, 1024, 0, stream>>>(deg, offs, cursor, N);
    k_edge<<<(E + 127) / 128, 256, 0, stream>>>(pos, batch, esrc, edst, eshift, cell,
                                                fw1, fb1, fw2, fb2, wz, Ai,
                                                ef, cursor, E);
    k_gather<<<(N + 3) / 4, 256, 0, stream>>>(ef, offs, out, N);
}